// Round 2
// baseline (1366.762 us; speedup 1.0000x reference)
//
#include <hip/hip_runtime.h>
#include <hip/hip_bf16.h>
#include <cstdint>
#include <cstddef>

#define TT 128
#define BBATCH 256
#define FFEAT 76
#define HDIM 64
#define NHEAD 4
#define DKH 16
#define DFF1 256
#define AH1 8

#define LOG2E 1.4426950408889634f

__device__ __forceinline__ float fast_sigmoid(float v) {
    float p = __builtin_amdgcn_exp2f(-v * LOG2E);
    return __builtin_amdgcn_rcpf(1.0f + p);
}
__device__ __forceinline__ float fast_tanh(float v) {
    // tanh(v) = 1 - 2/(exp(2v)+1); safe at +/-inf
    float p = __builtin_amdgcn_exp2f(v * (2.0f * LOG2E));
    return 1.0f - 2.0f * __builtin_amdgcn_rcpf(1.0f + p);
}

// ---------------------------------------------------------------------------
// Kernel 1: per-feature GRU(1,H) chains for features [f_base, f_base+gridDim.y).
// Block = 256 threads = 4 waves. Each wave handles one f and 2 batches.
// Lane l holds W_hh rows {l, l+64, l+128} (= r,z,n gate rows of hidden unit l)
// in 192 VGPRs. h broadcast via LDS. Writes hs (f_local,B,T,H) in bf16.
// ---------------------------------------------------------------------------
__global__ __launch_bounds__(256, 2) void gru_kernel(
    const float* __restrict__ x, const float* __restrict__ w_ih,
    const float* __restrict__ w_hh, const float* __restrict__ b_ih,
    const float* __restrict__ b_hh, int f_base, __hip_bfloat16* __restrict__ hs)
{
    const int f_loc = blockIdx.y;
    const int f     = f_base + f_loc;
    const int wave  = threadIdx.x >> 6;
    const int lane  = threadIdx.x & 63;
    const int b0    = blockIdx.x * 8 + wave * 2;   // 2 batches per wave

    __shared__ float h_lds[4][2][HDIM];
    __shared__ float x_lds[4][2][TT];

    // --- weights into registers ---
    float w[3][HDIM];
    {
        const float* whh = w_hh + (size_t)f * 192 * HDIM;
        #pragma unroll
        for (int r = 0; r < 3; ++r) {
            const float4* src = (const float4*)(whh + (size_t)(lane + 64 * r) * HDIM);
            #pragma unroll
            for (int jb = 0; jb < 16; ++jb) {
                float4 v = src[jb];
                w[r][4*jb+0] = v.x; w[r][4*jb+1] = v.y;
                w[r][4*jb+2] = v.z; w[r][4*jb+3] = v.w;
            }
        }
    }
    float wih[3], bih[3], bhh[3];
    #pragma unroll
    for (int r = 0; r < 3; ++r) {
        wih[r] = w_ih[f*192 + lane + 64*r];
        bih[r] = b_ih[f*192 + lane + 64*r];
        bhh[r] = b_hh[f*192 + lane + 64*r];
    }

    // --- preload this wave's x chains into LDS; init h ---
    #pragma unroll
    for (int bb = 0; bb < 2; ++bb) {
        int b = b0 + bb;
        for (int t = lane; t < TT; t += 64)
            x_lds[wave][bb][t] = x[(size_t)t * BBATCH * FFEAT + (size_t)b * FFEAT + f];
        h_lds[wave][bb][lane] = 0.0f;
    }
    float h[2] = {0.0f, 0.0f};
    __syncthreads();

    __hip_bfloat16* hs_base = hs + (((size_t)f_loc * BBATCH + b0) * TT) * HDIM + lane;

    for (int t = 0; t < TT; ++t) {
        float ar[2] = {0.f, 0.f}, az[2] = {0.f, 0.f}, an[2] = {0.f, 0.f};
        #pragma unroll
        for (int jb = 0; jb < 16; ++jb) {
            float hv[2][4];
            *(float4*)hv[0] = *(const float4*)&h_lds[wave][0][jb*4];
            *(float4*)hv[1] = *(const float4*)&h_lds[wave][1][jb*4];
            #pragma unroll
            for (int u = 0; u < 4; ++u) {
                int j = 4*jb + u;
                #pragma unroll
                for (int bb = 0; bb < 2; ++bb) {
                    ar[bb] = fmaf(w[0][j], hv[bb][u], ar[bb]);
                    az[bb] = fmaf(w[1][j], hv[bb][u], az[bb]);
                    an[bb] = fmaf(w[2][j], hv[bb][u], an[bb]);
                }
            }
        }
        #pragma unroll
        for (int bb = 0; bb < 2; ++bb) {
            float xv = x_lds[wave][bb][t];
            float rg = fast_sigmoid(fmaf(xv, wih[0], bih[0]) + ar[bb] + bhh[0]);
            float zg = fast_sigmoid(fmaf(xv, wih[1], bih[1]) + az[bb] + bhh[1]);
            float ng = fast_tanh(fmaf(xv, wih[2], bih[2]) + rg * (an[bb] + bhh[2]));
            float hn = fmaf(zg, h[bb] - ng, ng);
            h[bb] = hn;
            hs_base[((size_t)bb * TT + t) * HDIM] = __float2bfloat16(hn);
            h_lds[wave][bb][lane] = hn;
        }
    }
}

// ---------------------------------------------------------------------------
// Kernel 2: per-(f,b) time attention for features [f_base, f_base+gridDim.y).
// Block = 128 threads (one per t).
// ---------------------------------------------------------------------------
__global__ __launch_bounds__(128) void attn_kernel(
    const __hip_bfloat16* __restrict__ hs, const float* __restrict__ Wt,
    const float* __restrict__ Wx, const float* __restrict__ rate,
    int f_base, float* __restrict__ emb)
{
    const int b     = blockIdx.x;
    const int f_loc = blockIdx.y;
    const int f     = f_base + f_loc;
    const int tid   = threadIdx.x;

    __shared__ float h_s[TT][HDIM + 1];   // pad: conflict-free row writes
    __shared__ float wx_s[HDIM][AH1];
    __shared__ float wt_s[HDIM][AH1];
    __shared__ float q_s[AH1];
    __shared__ float a_s[TT];
    __shared__ float redm[2], redp[2];
    __shared__ float partial_s[HDIM];

    for (int i = tid; i < HDIM * AH1; i += 128) {
        ((float*)wx_s)[i] = Wx[(size_t)f * HDIM * AH1 + i];
        ((float*)wt_s)[i] = Wt[(size_t)f * HDIM * AH1 + i];
    }

    // stage own h row (bf16 -> f32), keep in registers too
    float hreg[HDIM];
    {
        const __hip_bfloat16* src = hs + (((size_t)f_loc * BBATCH + b) * TT + tid) * HDIM;
        #pragma unroll
        for (int c = 0; c < 8; ++c) {
            uint4 u = ((const uint4*)src)[c];
            unsigned vals[4] = {u.x, u.y, u.z, u.w};
            #pragma unroll
            for (int p = 0; p < 4; ++p) {
                hreg[c*8 + 2*p]     = __uint_as_float(vals[p] << 16);
                hreg[c*8 + 2*p + 1] = __uint_as_float(vals[p] & 0xffff0000u);
            }
        }
        #pragma unroll
        for (int j = 0; j < HDIM; ++j) h_s[tid][j] = hreg[j];
    }
    __syncthreads();

    // q from last hidden state
    if (tid < AH1) {
        float acc = 0.f;
        #pragma unroll
        for (int j = 0; j < HDIM; ++j) acc += h_s[TT-1][j] * wt_s[j][tid];
        q_s[tid] = acc;
    }
    __syncthreads();

    // k-projection from registers, score e_t
    float k[AH1];
    #pragma unroll
    for (int a = 0; a < AH1; ++a) k[a] = 0.f;
    #pragma unroll
    for (int j = 0; j < HDIM; ++j) {
        float hv = hreg[j];
        #pragma unroll
        for (int a = 0; a < AH1; ++a) k[a] = fmaf(hv, wx_s[j][a], k[a]);
    }
    float dp = 0.f;
    #pragma unroll
    for (int a = 0; a < AH1; ++a) dp += k[a] * q_s[a];

    float sig   = fast_sigmoid(dp);
    float rs    = fast_sigmoid(rate[f]);
    float decay = (float)(TT - tid);
    float denom = rs * (__logf(2.72f + (1.0f - sig)) * decay);
    float e = fmaxf(sig / denom, 0.0f);

    // softmax over 128 threads (2 waves)
    float m = e;
    #pragma unroll
    for (int off = 32; off > 0; off >>= 1) m = fmaxf(m, __shfl_xor(m, off, 64));
    if ((tid & 63) == 0) redm[tid >> 6] = m;
    __syncthreads();
    m = fmaxf(redm[0], redm[1]);
    float p = __builtin_amdgcn_exp2f((e - m) * LOG2E);
    float s = p;
    #pragma unroll
    for (int off = 32; off > 0; off >>= 1) s += __shfl_xor(s, off, 64);
    if ((tid & 63) == 0) redp[tid >> 6] = s;
    __syncthreads();
    s = redp[0] + redp[1];
    a_s[tid] = p / s;
    __syncthreads();

    // emb[b,f,:] = sum_t a_t * h_t
    const int j    = tid & 63;
    const int half = tid >> 6;
    float acc = 0.f;
    const int t0 = half * 64;
    #pragma unroll 8
    for (int t2 = t0; t2 < t0 + 64; ++t2)
        acc = fmaf(a_s[t2], h_s[t2][j], acc);
    if (half) partial_s[j] = acc;
    __syncthreads();
    if (!half) emb[((size_t)b * FFEAT + f) * HDIM + j] = acc + partial_s[j];
}

// ---------------------------------------------------------------------------
// Kernel 3: per-batch tail — MHA over features + FFN + final attention + head.
// Block = 256 threads, one block per b.
// ---------------------------------------------------------------------------
__global__ __launch_bounds__(256) void tail_kernel(
    const float* __restrict__ emb,
    const float* __restrict__ wq, const float* __restrict__ bq,
    const float* __restrict__ wk, const float* __restrict__ bk,
    const float* __restrict__ wv, const float* __restrict__ bv,
    const float* __restrict__ wo, const float* __restrict__ bo,
    const float* __restrict__ w1, const float* __restrict__ b1,
    const float* __restrict__ w2, const float* __restrict__ b2,
    const float* __restrict__ faq, const float* __restrict__ fabq,
    const float* __restrict__ fak, const float* __restrict__ fabk,
    const float* __restrict__ fav, const float* __restrict__ fabv,
    const float* __restrict__ o0w, const float* __restrict__ o0b,
    const float* __restrict__ o1w, const float* __restrict__ o1b,
    float* __restrict__ out)
{
    const int b   = blockIdx.x;
    const int tid = threadIdx.x;
    const int c   = tid & 63;     // column role
    const int q4  = tid >> 6;     // row-group role (0..3)

    __shared__ float emb_s[FFEAT][HDIM];   // becomes ctx2, then ctx3
    __shared__ float ctx_s[FFEAT][HDIM];   // MHA ctx; then FFN hid chunk; then fk; then scratch
    __shared__ float scr[4672];            // qh/kh/vh (3*1216) + wslice(1024) OR 64x64 weight stage
    __shared__ float fq_s[HDIM];
    __shared__ float v_s[HDIM];
    __shared__ float fe_s[FFEAT];
    __shared__ float sm_s[FFEAT];

    for (int i = tid; i < FFEAT * HDIM; i += 256)
        ((float*)emb_s)[i] = emb[(size_t)b * FFEAT * HDIM + i];
    for (int i = tid; i < FFEAT * HDIM; i += 256)
        ((float*)ctx_s)[i] = 0.f;
    __syncthreads();

    float* qh  = scr;
    float* kh  = scr + 1216;
    float* vh  = scr + 2432;
    float* wsl = scr + 3648;   // [64][16]

    // ---- MHA heads ----
    for (int hh = 0; hh < NHEAD; ++hh) {
        // qh
        for (int i = tid; i < HDIM * DKH; i += 256)
            wsl[i] = wq[(i / DKH) * HDIM + hh * DKH + (i % DKH)];
        __syncthreads();
        for (int e = tid; e < FFEAT * DKH; e += 256) {
            int i = e / DKH, cc = e % DKH;
            float acc = bq[hh * DKH + cc];
            #pragma unroll
            for (int jj = 0; jj < HDIM; ++jj) acc += emb_s[i][jj] * wsl[jj * DKH + cc];
            qh[e] = acc;
        }
        __syncthreads();
        // kh
        for (int i = tid; i < HDIM * DKH; i += 256)
            wsl[i] = wk[(i / DKH) * HDIM + hh * DKH + (i % DKH)];
        __syncthreads();
        for (int e = tid; e < FFEAT * DKH; e += 256) {
            int i = e / DKH, cc = e % DKH;
            float acc = bk[hh * DKH + cc];
            #pragma unroll
            for (int jj = 0; jj < HDIM; ++jj) acc += emb_s[i][jj] * wsl[jj * DKH + cc];
            kh[e] = acc;
        }
        __syncthreads();
        // vh
        for (int i = tid; i < HDIM * DKH; i += 256)
            wsl[i] = wv[(i / DKH) * HDIM + hh * DKH + (i % DKH)];
        __syncthreads();
        for (int e = tid; e < FFEAT * DKH; e += 256) {
            int i = e / DKH, cc = e % DKH;
            float acc = bv[hh * DKH + cc];
            #pragma unroll
            for (int jj = 0; jj < HDIM; ++jj) acc += emb_s[i][jj] * wsl[jj * DKH + cc];
            vh[e] = acc;
        }
        __syncthreads();

        // scores + softmax + ctx, one row per thread
        if (tid < FFEAT) {
            float sc[FFEAT];
            #pragma unroll
            for (int kk = 0; kk < FFEAT; ++kk) {
                float acc = 0.f;
                #pragma unroll
                for (int cc = 0; cc < DKH; ++cc) acc += qh[tid*DKH + cc] * kh[kk*DKH + cc];
                sc[kk] = acc * 0.25f;   // 1/sqrt(16)
            }
            float mm = sc[0];
            #pragma unroll
            for (int kk = 1; kk < FFEAT; ++kk) mm = fmaxf(mm, sc[kk]);
            float ss = 0.f;
            #pragma unroll
            for (int kk = 0; kk < FFEAT; ++kk) {
                sc[kk] = __builtin_amdgcn_exp2f((sc[kk] - mm) * LOG2E);
                ss += sc[kk];
            }
            float inv = 1.0f / ss;
            #pragma unroll
            for (int cc = 0; cc < DKH; ++cc) {
                float acc = 0.f;
                #pragma unroll
                for (int kk = 0; kk < FFEAT; ++kk) acc += sc[kk] * vh[kk*DKH + cc];
                ctx_s[tid][hh*DKH + cc] = acc * inv;
            }
        }
        __syncthreads();
    }

    // ---- out projection + residual: emb_s = emb_s + ctx_s @ wo + bo ----
    for (int i = tid; i < HDIM * HDIM; i += 256) scr[i] = wo[i];
    __syncthreads();
    for (int e = tid; e < FFEAT * HDIM; e += 256) {
        int i = e >> 6, cc = e & 63;
        float acc = bo[cc];
        #pragma unroll
        for (int jj = 0; jj < HDIM; ++jj) acc += ctx_s[i][jj] * scr[jj * HDIM + cc];
        emb_s[i][cc] += acc;
    }
    __syncthreads();

    // ---- FFN (chunked over DFF) + residual ----
    float facc[19];
    #pragma unroll
    for (int ii = 0; ii < 19; ++ii) facc[ii] = 0.f;
    for (int kc = 0; kc < 4; ++kc) {
        for (int i = tid; i < 4096; i += 256)
            scr[i] = w1[(size_t)(i >> 6) * DFF1 + kc * 64 + (i & 63)];
        __syncthreads();
        for (int e = tid; e < FFEAT * 64; e += 256) {
            int i = e >> 6, kk = e & 63;
            float acc = b1[kc * 64 + kk];
            #pragma unroll
            for (int jj = 0; jj < HDIM; ++jj) acc += emb_s[i][jj] * scr[jj * 64 + kk];
            ctx_s[i][kk] = fmaxf(acc, 0.f);
        }
        __syncthreads();
        for (int i = tid; i < 4096; i += 256)
            scr[i] = w2[(size_t)(kc * 64 + (i >> 6)) * HDIM + (i & 63)];
        __syncthreads();
        #pragma unroll
        for (int ii = 0; ii < 19; ++ii) {
            int i = q4 + 4 * ii;
            float acc = facc[ii];
            #pragma unroll
            for (int kk = 0; kk < 64; ++kk) acc += ctx_s[i][kk] * scr[kk * 64 + c];
            facc[ii] = acc;
        }
        __syncthreads();
    }
    #pragma unroll
    for (int ii = 0; ii < 19; ++ii) {
        int i = q4 + 4 * ii;
        emb_s[i][c] += facc[ii] + b2[c];
    }
    __syncthreads();

    // ---- final attention (type 'mul') ----
    for (int i = tid; i < 4096; i += 256) scr[i] = faq[i];
    __syncthreads();
    if (tid < HDIM) {
        float acc = fabq[tid];
        #pragma unroll
        for (int jj = 0; jj < HDIM; ++jj) acc += emb_s[FFEAT-1][jj] * scr[jj * HDIM + tid];
        fq_s[tid] = acc;
    }
    __syncthreads();
    for (int i = tid; i < 4096; i += 256) scr[i] = fak[i];
    __syncthreads();
    for (int e = tid; e < FFEAT * HDIM; e += 256) {
        int i = e >> 6, cc = e & 63;
        float acc = fabk[cc];
        #pragma unroll
        for (int jj = 0; jj < HDIM; ++jj) acc += emb_s[i][jj] * scr[jj * HDIM + cc];
        ctx_s[i][cc] = acc;
    }
    __syncthreads();
    if (tid < FFEAT) {
        float acc = 0.f;
        #pragma unroll
        for (int cc = 0; cc < HDIM; ++cc) acc += ctx_s[tid][cc] * fq_s[cc];
        fe_s[tid] = acc;
    }
    __syncthreads();
    if (tid == 0) {
        float mm = fe_s[0];
        for (int i = 1; i < FFEAT; ++i) mm = fmaxf(mm, fe_s[i]);
        float ss = 0.f;
        for (int i = 0; i < FFEAT; ++i) {
            float pp = __builtin_amdgcn_exp2f((fe_s[i] - mm) * LOG2E);
            sm_s[i] = pp; ss += pp;
        }
        float inv = 1.0f / ss;
        for (int i = 0; i < FFEAT; ++i) sm_s[i] *= inv;
    }
    __syncthreads();
    for (int i = tid; i < 4096; i += 256) scr[i] = fav[i];
    __syncthreads();
    {
        float acc = 0.f;
        for (int i = q4; i < FFEAT; i += 4) {
            float dot = fabv[c];
            #pragma unroll
            for (int jj = 0; jj < HDIM; ++jj) dot += emb_s[i][jj] * scr[jj * HDIM + c];
            acc += sm_s[i] * dot;
        }
        ((float*)ctx_s)[q4 * 64 + c] = acc;
    }
    __syncthreads();
    if (tid < HDIM) {
        v_s[tid] = ((float*)ctx_s)[tid] + ((float*)ctx_s)[64 + tid] +
                   ((float*)ctx_s)[128 + tid] + ((float*)ctx_s)[192 + tid];
    }
    __syncthreads();

    // ---- output head ----
    for (int i = tid; i < 4096; i += 256) scr[i] = o0w[i];
    __syncthreads();
    if (tid < HDIM) {
        float acc = o0b[tid];
        #pragma unroll
        for (int jj = 0; jj < HDIM; ++jj) acc += v_s[jj] * scr[jj * HDIM + tid];
        ((float*)ctx_s)[512 + tid] = fmaxf(acc, 0.f);
    }
    __syncthreads();
    if (tid == 0) {
        float acc = o1b[0];
        #pragma unroll
        for (int jj = 0; jj < HDIM; ++jj) acc += ((float*)ctx_s)[512 + jj] * o1w[jj];
        out[b] = fast_sigmoid(acc);
    }
}

// ws-size diagnostic: if workspace is too small even for 1-feature chunks,
// encode its size (MiB) in d_out
__global__ void ws_report_kernel(float* out, int n, float ws_mib) {
    int i = blockIdx.x * blockDim.x + threadIdx.x;
    if (i < n) out[i] = ws_mib;
}

extern "C" void kernel_launch(void* const* d_in, const int* in_sizes, int n_in,
                              void* d_out, int out_size, void* d_ws, size_t ws_size,
                              hipStream_t stream)
{
    const float* x     = (const float*)d_in[0];
    const float* w_ih  = (const float*)d_in[1];
    const float* w_hh  = (const float*)d_in[2];
    const float* b_ih  = (const float*)d_in[3];
    const float* b_hh  = (const float*)d_in[4];
    const float* attWt = (const float*)d_in[5];
    const float* attWx = (const float*)d_in[6];
    const float* attRt = (const float*)d_in[7];
    const float* wq    = (const float*)d_in[8];
    const float* bq    = (const float*)d_in[9];
    const float* wk    = (const float*)d_in[10];
    const float* bk    = (const float*)d_in[11];
    const float* wv    = (const float*)d_in[12];
    const float* bv    = (const float*)d_in[13];
    const float* wo    = (const float*)d_in[14];
    const float* bo    = (const float*)d_in[15];
    const float* w1    = (const float*)d_in[16];
    const float* b1    = (const float*)d_in[17];
    const float* w2    = (const float*)d_in[18];
    const float* b2    = (const float*)d_in[19];
    const float* faq   = (const float*)d_in[20];
    const float* fabq  = (const float*)d_in[21];
    const float* fak   = (const float*)d_in[22];
    const float* fabk  = (const float*)d_in[23];
    const float* fav   = (const float*)d_in[24];
    const float* fabv  = (const float*)d_in[25];
    const float* o0w   = (const float*)d_in[26];
    const float* o0b   = (const float*)d_in[27];
    const float* o1w   = (const float*)d_in[28];
    const float* o1b   = (const float*)d_in[29];
    float* out = (float*)d_out;

    const size_t emb_bytes = (size_t)BBATCH * FFEAT * HDIM * 4;       // fp32, 4.75 MiB

    // choose the largest feature-chunk whose bf16 hs buffer fits the workspace
    const int chunk_opts[6] = {76, 38, 19, 4, 2, 1};
    int FC = 0;
    for (int i = 0; i < 6; ++i) {
        size_t hs_b = (size_t)chunk_opts[i] * BBATCH * TT * HDIM * 2;
        if (emb_bytes + hs_b <= ws_size) { FC = chunk_opts[i]; break; }
    }
    if (FC == 0) {
        ws_report_kernel<<<dim3((out_size + 255) / 256), dim3(256), 0, stream>>>(
            out, out_size, (float)((double)ws_size / (1024.0 * 1024.0)));
        return;
    }

    float* emb = (float*)d_ws;
    __hip_bfloat16* hs = (__hip_bfloat16*)((char*)d_ws + emb_bytes);

    for (int f0 = 0; f0 < FFEAT; f0 += FC) {
        gru_kernel<<<dim3(BBATCH / 8, FC), dim3(256), 0, stream>>>(
            x, w_ih, w_hh, b_ih, b_hh, f0, hs);
        attn_kernel<<<dim3(BBATCH, FC), dim3(128), 0, stream>>>(
            hs, attWt, attWx, attRt, f0, emb);
    }
    tail_kernel<<<dim3(BBATCH), dim3(256), 0, stream>>>(
        emb, wq, bq, wk, bk, wv, bv, wo, bo, w1, b1, w2, b2,
        faq, fabq, fak, fabk, fav, fabv, o0w, o0b, o1w, o1b, out);
}

// Round 3
// 796.569 us; speedup vs baseline: 1.7158x; 1.7158x over previous
//
#include <hip/hip_runtime.h>
#include <hip/hip_bf16.h>
#include <cstdint>
#include <cstddef>

#define TT 128
#define BBATCH 256
#define FFEAT 76
#define HDIM 64
#define NHEAD 4
#define DKH 16
#define DFF1 256
#define AH1 8

#define LOG2E 1.4426950408889634f

typedef __attribute__((ext_vector_type(8))) short bf16x8;
typedef __attribute__((ext_vector_type(4))) float f32x4;

__device__ __forceinline__ float fast_sigmoid(float v) {
    float p = __builtin_amdgcn_exp2f(-v * LOG2E);
    return __builtin_amdgcn_rcpf(1.0f + p);
}
__device__ __forceinline__ float fast_tanh(float v) {
    float p = __builtin_amdgcn_exp2f(v * (2.0f * LOG2E));
    return 1.0f - 2.0f * __builtin_amdgcn_rcpf(1.0f + p);
}
__device__ __forceinline__ short f2bf(float x) {
    __hip_bfloat16 h = __float2bfloat16(x);
    return *reinterpret_cast<short*>(&h);
}

// ---------------------------------------------------------------------------
// Kernel 1: MFMA GRU. One block = (feature, 64-batch quarter), 512 thr = 8 waves.
// Per t: G[64 b][192 g] = h_bf16 @ Whh_bf16^T via 16x16x32 MFMA (12/wave),
// gates lane-local (r,z,n share reg/lane slots across the wave's 3 N-tiles),
// h kept fp32 in regs, bf16 round-trip through LDS for the next step's A-frags.
// ---------------------------------------------------------------------------
__global__ __launch_bounds__(512, 2) void gru_mfma_kernel(
    const float* __restrict__ x, const float* __restrict__ w_ih,
    const float* __restrict__ w_hh, const float* __restrict__ b_ih,
    const float* __restrict__ b_hh, int f_base, __hip_bfloat16* __restrict__ hs)
{
    const int f_loc = blockIdx.y;
    const int f     = f_base + f_loc;
    const int b0    = blockIdx.x * 64;
    const int tid   = threadIdx.x;
    const int wave  = tid >> 6;
    const int lane  = tid & 63;
    const int col   = lane & 15;
    const int quad  = lane >> 4;
    const int ug    = wave & 3;          // unit group: units ug*16 .. ug*16+15
    const int mt0   = (wave >> 2) * 2;   // this wave's two M-tiles
    const int u     = ug * 16 + col;     // this lane's hidden unit

    __shared__ __align__(16) short h_lds[64][72];   // [b][j] bf16, stride 72 (2-way bank = free)
    __shared__ __align__(16) float x_lds[TT][64];   // [t][b]

    // stage x (one-time)
    for (int i = tid; i < TT * 64; i += 512) {
        int t = i >> 6, b = i & 63;
        x_lds[t][b] = x[(size_t)t * BBATCH * FFEAT + (size_t)(b0 + b) * FFEAT + f];
    }
    for (int i = tid; i < 64 * 72; i += 512) ((short*)h_lds)[i] = 0;

    // B fragments: B[k][n] = Whh[g=n][j=k], bf16. 6 frags resident all loop.
    bf16x8 bfr[3][2];
    {
        const float* whh_f = w_hh + (size_t)f * 192 * 64;
        #pragma unroll
        for (int gi = 0; gi < 3; ++gi) {
            const float* row = whh_f + (size_t)(gi * 64 + u) * 64;
            #pragma unroll
            for (int kq = 0; kq < 2; ++kq) {
                const float* src = row + kq * 32 + quad * 8;
                bf16x8 fr;
                #pragma unroll
                for (int j = 0; j < 8; ++j) fr[j] = f2bf(src[j]);
                bfr[gi][kq] = fr;
            }
        }
    }
    // per-lane gate constants
    const float wihr  = w_ih[f*192 + u];
    const float wihz  = w_ih[f*192 + 64 + u];
    const float wihn  = w_ih[f*192 + 128 + u];
    const float brz_r = b_ih[f*192 + u]      + b_hh[f*192 + u];
    const float brz_z = b_ih[f*192 + 64 + u] + b_hh[f*192 + 64 + u];
    const float bih_n = b_ih[f*192 + 128 + u];
    const float bhh_n = b_hh[f*192 + 128 + u];

    float hprev[2][4] = {{0.f,0.f,0.f,0.f},{0.f,0.f,0.f,0.f}};
    __syncthreads();

    for (int t = 0; t < TT; ++t) {
        // A-frags: A[m][k] = h_{t-1}[b = mtile*16 + (lane&15)][k = quad*8+j]
        bf16x8 afr[2][2];
        #pragma unroll
        for (int mi = 0; mi < 2; ++mi)
            #pragma unroll
            for (int kq = 0; kq < 2; ++kq)
                afr[mi][kq] = *(const bf16x8*)&h_lds[(mt0+mi)*16 + col][kq*32 + quad*8];
        __syncthreads();   // all reads of h_{t-1} done before anyone overwrites

        f32x4 acc[2][3];
        #pragma unroll
        for (int mi = 0; mi < 2; ++mi)
            #pragma unroll
            for (int gi = 0; gi < 3; ++gi) {
                f32x4 a = {0.f, 0.f, 0.f, 0.f};
                a = __builtin_amdgcn_mfma_f32_16x16x32_bf16(afr[mi][0], bfr[gi][0], a, 0, 0, 0);
                a = __builtin_amdgcn_mfma_f32_16x16x32_bf16(afr[mi][1], bfr[gi][1], a, 0, 0, 0);
                acc[mi][gi] = a;
            }

        #pragma unroll
        for (int mi = 0; mi < 2; ++mi) {
            const int brow = (mt0 + mi) * 16 + quad * 4;
            float4 xv = *(const float4*)&x_lds[t][brow];   // broadcast within quad
            #pragma unroll
            for (int r = 0; r < 4; ++r) {
                float xb = (&xv.x)[r];
                float R  = acc[mi][0][r] + fmaf(xb, wihr, brz_r);
                float Z  = acc[mi][1][r] + fmaf(xb, wihz, brz_z);
                float NH = acc[mi][2][r] + bhh_n;
                float NX = fmaf(xb, wihn, bih_n);
                float rg = fast_sigmoid(R);
                float zg = fast_sigmoid(Z);
                float ng = fast_tanh(fmaf(rg, NH, NX));
                float hn = fmaf(zg, hprev[mi][r] - ng, ng);   // (1-z)n + z h
                hprev[mi][r] = hn;
                short hb = f2bf(hn);
                h_lds[brow + r][u] = hb;
                hs[(((size_t)f_loc * BBATCH + b0 + brow + r) * TT + t) * HDIM + u] =
                    *reinterpret_cast<__hip_bfloat16*>(&hb);
            }
        }
        __syncthreads();   // h_t visible before next iteration's reads
    }
}

// ---------------------------------------------------------------------------
// Kernel 2: per-(f,b) time attention. Block = 128 threads (one per t).
// ---------------------------------------------------------------------------
__global__ __launch_bounds__(128) void attn_kernel(
    const __hip_bfloat16* __restrict__ hs, const float* __restrict__ Wt,
    const float* __restrict__ Wx, const float* __restrict__ rate,
    int f_base, float* __restrict__ emb)
{
    const int b     = blockIdx.x;
    const int f_loc = blockIdx.y;
    const int f     = f_base + f_loc;
    const int tid   = threadIdx.x;

    __shared__ float h_s[TT][HDIM + 1];
    __shared__ float wx_s[HDIM][AH1];
    __shared__ float wt_s[HDIM][AH1];
    __shared__ float q_s[AH1];
    __shared__ float a_s[TT];
    __shared__ float redm[2], redp[2];
    __shared__ float partial_s[HDIM];

    for (int i = tid; i < HDIM * AH1; i += 128) {
        ((float*)wx_s)[i] = Wx[(size_t)f * HDIM * AH1 + i];
        ((float*)wt_s)[i] = Wt[(size_t)f * HDIM * AH1 + i];
    }

    float hreg[HDIM];
    {
        const __hip_bfloat16* src = hs + (((size_t)f_loc * BBATCH + b) * TT + tid) * HDIM;
        #pragma unroll
        for (int c = 0; c < 8; ++c) {
            uint4 u4 = ((const uint4*)src)[c];
            unsigned vals[4] = {u4.x, u4.y, u4.z, u4.w};
            #pragma unroll
            for (int p = 0; p < 4; ++p) {
                hreg[c*8 + 2*p]     = __uint_as_float(vals[p] << 16);
                hreg[c*8 + 2*p + 1] = __uint_as_float(vals[p] & 0xffff0000u);
            }
        }
        #pragma unroll
        for (int j = 0; j < HDIM; ++j) h_s[tid][j] = hreg[j];
    }
    __syncthreads();

    if (tid < AH1) {
        float acc = 0.f;
        #pragma unroll
        for (int j = 0; j < HDIM; ++j) acc += h_s[TT-1][j] * wt_s[j][tid];
        q_s[tid] = acc;
    }
    __syncthreads();

    float k[AH1];
    #pragma unroll
    for (int a = 0; a < AH1; ++a) k[a] = 0.f;
    #pragma unroll
    for (int j = 0; j < HDIM; ++j) {
        float hv = hreg[j];
        #pragma unroll
        for (int a = 0; a < AH1; ++a) k[a] = fmaf(hv, wx_s[j][a], k[a]);
    }
    float dp = 0.f;
    #pragma unroll
    for (int a = 0; a < AH1; ++a) dp += k[a] * q_s[a];

    float sig   = fast_sigmoid(dp);
    float rs    = fast_sigmoid(rate[f]);
    float decay = (float)(TT - tid);
    float denom = rs * (__logf(2.72f + (1.0f - sig)) * decay);
    float e = fmaxf(sig / denom, 0.0f);

    float m = e;
    #pragma unroll
    for (int off = 32; off > 0; off >>= 1) m = fmaxf(m, __shfl_xor(m, off, 64));
    if ((tid & 63) == 0) redm[tid >> 6] = m;
    __syncthreads();
    m = fmaxf(redm[0], redm[1]);
    float p = __builtin_amdgcn_exp2f((e - m) * LOG2E);
    float s = p;
    #pragma unroll
    for (int off = 32; off > 0; off >>= 1) s += __shfl_xor(s, off, 64);
    if ((tid & 63) == 0) redp[tid >> 6] = s;
    __syncthreads();
    s = redp[0] + redp[1];
    a_s[tid] = p / s;
    __syncthreads();

    const int j    = tid & 63;
    const int half = tid >> 6;
    float acc = 0.f;
    const int t0 = half * 64;
    #pragma unroll 8
    for (int t2 = t0; t2 < t0 + 64; ++t2)
        acc = fmaf(a_s[t2], h_s[t2][j], acc);
    if (half) partial_s[j] = acc;
    __syncthreads();
    if (!half) emb[((size_t)b * FFEAT + f) * HDIM + j] = acc + partial_s[j];
}

// ---------------------------------------------------------------------------
// Kernel 3: per-batch tail — MHA over features + FFN + final attention + head.
// ---------------------------------------------------------------------------
__global__ __launch_bounds__(256) void tail_kernel(
    const float* __restrict__ emb,
    const float* __restrict__ wq, const float* __restrict__ bq,
    const float* __restrict__ wk, const float* __restrict__ bk,
    const float* __restrict__ wv, const float* __restrict__ bv,
    const float* __restrict__ wo, const float* __restrict__ bo,
    const float* __restrict__ w1, const float* __restrict__ b1,
    const float* __restrict__ w2, const float* __restrict__ b2,
    const float* __restrict__ faq, const float* __restrict__ fabq,
    const float* __restrict__ fak, const float* __restrict__ fabk,
    const float* __restrict__ fav, const float* __restrict__ fabv,
    const float* __restrict__ o0w, const float* __restrict__ o0b,
    const float* __restrict__ o1w, const float* __restrict__ o1b,
    float* __restrict__ out)
{
    const int b   = blockIdx.x;
    const int tid = threadIdx.x;
    const int c   = tid & 63;
    const int q4  = tid >> 6;

    __shared__ float emb_s[FFEAT][HDIM];
    __shared__ float ctx_s[FFEAT][HDIM];
    __shared__ float scr[4672];
    __shared__ float fq_s[HDIM];
    __shared__ float v_s[HDIM];
    __shared__ float fe_s[FFEAT];
    __shared__ float sm_s[FFEAT];

    for (int i = tid; i < FFEAT * HDIM; i += 256)
        ((float*)emb_s)[i] = emb[(size_t)b * FFEAT * HDIM + i];
    for (int i = tid; i < FFEAT * HDIM; i += 256)
        ((float*)ctx_s)[i] = 0.f;
    __syncthreads();

    float* qh  = scr;
    float* kh  = scr + 1216;
    float* vh  = scr + 2432;
    float* wsl = scr + 3648;

    for (int hh = 0; hh < NHEAD; ++hh) {
        for (int i = tid; i < HDIM * DKH; i += 256)
            wsl[i] = wq[(i / DKH) * HDIM + hh * DKH + (i % DKH)];
        __syncthreads();
        for (int e = tid; e < FFEAT * DKH; e += 256) {
            int i = e / DKH, cc = e % DKH;
            float acc = bq[hh * DKH + cc];
            #pragma unroll
            for (int jj = 0; jj < HDIM; ++jj) acc += emb_s[i][jj] * wsl[jj * DKH + cc];
            qh[e] = acc;
        }
        __syncthreads();
        for (int i = tid; i < HDIM * DKH; i += 256)
            wsl[i] = wk[(i / DKH) * HDIM + hh * DKH + (i % DKH)];
        __syncthreads();
        for (int e = tid; e < FFEAT * DKH; e += 256) {
            int i = e / DKH, cc = e % DKH;
            float acc = bk[hh * DKH + cc];
            #pragma unroll
            for (int jj = 0; jj < HDIM; ++jj) acc += emb_s[i][jj] * wsl[jj * DKH + cc];
            kh[e] = acc;
        }
        __syncthreads();
        for (int i = tid; i < HDIM * DKH; i += 256)
            wsl[i] = wv[(i / DKH) * HDIM + hh * DKH + (i % DKH)];
        __syncthreads();
        for (int e = tid; e < FFEAT * DKH; e += 256) {
            int i = e / DKH, cc = e % DKH;
            float acc = bv[hh * DKH + cc];
            #pragma unroll
            for (int jj = 0; jj < HDIM; ++jj) acc += emb_s[i][jj] * wsl[jj * DKH + cc];
            vh[e] = acc;
        }
        __syncthreads();

        if (tid < FFEAT) {
            float sc[FFEAT];
            #pragma unroll
            for (int kk = 0; kk < FFEAT; ++kk) {
                float acc = 0.f;
                #pragma unroll
                for (int cc = 0; cc < DKH; ++cc) acc += qh[tid*DKH + cc] * kh[kk*DKH + cc];
                sc[kk] = acc * 0.25f;
            }
            float mm = sc[0];
            #pragma unroll
            for (int kk = 1; kk < FFEAT; ++kk) mm = fmaxf(mm, sc[kk]);
            float ss = 0.f;
            #pragma unroll
            for (int kk = 0; kk < FFEAT; ++kk) {
                sc[kk] = __builtin_amdgcn_exp2f((sc[kk] - mm) * LOG2E);
                ss += sc[kk];
            }
            float inv = 1.0f / ss;
            #pragma unroll
            for (int cc = 0; cc < DKH; ++cc) {
                float acc = 0.f;
                #pragma unroll
                for (int kk = 0; kk < FFEAT; ++kk) acc += sc[kk] * vh[kk*DKH + cc];
                ctx_s[tid][hh*DKH + cc] = acc * inv;
            }
        }
        __syncthreads();
    }

    for (int i = tid; i < HDIM * HDIM; i += 256) scr[i] = wo[i];
    __syncthreads();
    for (int e = tid; e < FFEAT * HDIM; e += 256) {
        int i = e >> 6, cc = e & 63;
        float acc = bo[cc];
        #pragma unroll
        for (int jj = 0; jj < HDIM; ++jj) acc += ctx_s[i][jj] * scr[jj * HDIM + cc];
        emb_s[i][cc] += acc;
    }
    __syncthreads();

    float facc[19];
    #pragma unroll
    for (int ii = 0; ii < 19; ++ii) facc[ii] = 0.f;
    for (int kc = 0; kc < 4; ++kc) {
        for (int i = tid; i < 4096; i += 256)
            scr[i] = w1[(size_t)(i >> 6) * DFF1 + kc * 64 + (i & 63)];
        __syncthreads();
        for (int e = tid; e < FFEAT * 64; e += 256) {
            int i = e >> 6, kk = e & 63;
            float acc = b1[kc * 64 + kk];
            #pragma unroll
            for (int jj = 0; jj < HDIM; ++jj) acc += emb_s[i][jj] * scr[jj * 64 + kk];
            ctx_s[i][kk] = fmaxf(acc, 0.f);
        }
        __syncthreads();
        for (int i = tid; i < 4096; i += 256)
            scr[i] = w2[(size_t)(kc * 64 + (i >> 6)) * HDIM + (i & 63)];
        __syncthreads();
        #pragma unroll
        for (int ii = 0; ii < 19; ++ii) {
            int i = q4 + 4 * ii;
            float acc = facc[ii];
            #pragma unroll
            for (int kk = 0; kk < 64; ++kk) acc += ctx_s[i][kk] * scr[kk * 64 + c];
            facc[ii] = acc;
        }
        __syncthreads();
    }
    #pragma unroll
    for (int ii = 0; ii < 19; ++ii) {
        int i = q4 + 4 * ii;
        emb_s[i][c] += facc[ii] + b2[c];
    }
    __syncthreads();

    for (int i = tid; i < 4096; i += 256) scr[i] = faq[i];
    __syncthreads();
    if (tid < HDIM) {
        float acc = fabq[tid];
        #pragma unroll
        for (int jj = 0; jj < HDIM; ++jj) acc += emb_s[FFEAT-1][jj] * scr[jj * HDIM + tid];
        fq_s[tid] = acc;
    }
    __syncthreads();
    for (int i = tid; i < 4096; i += 256) scr[i] = fak[i];
    __syncthreads();
    for (int e = tid; e < FFEAT * HDIM; e += 256) {
        int i = e >> 6, cc = e & 63;
        float acc = fabk[cc];
        #pragma unroll
        for (int jj = 0; jj < HDIM; ++jj) acc += emb_s[i][jj] * scr[jj * HDIM + cc];
        ctx_s[i][cc] = acc;
    }
    __syncthreads();
    if (tid < FFEAT) {
        float acc = 0.f;
        #pragma unroll
        for (int cc = 0; cc < HDIM; ++cc) acc += ctx_s[tid][cc] * fq_s[cc];
        fe_s[tid] = acc;
    }
    __syncthreads();
    if (tid == 0) {
        float mm = fe_s[0];
        for (int i = 1; i < FFEAT; ++i) mm = fmaxf(mm, fe_s[i]);
        float ss = 0.f;
        for (int i = 0; i < FFEAT; ++i) {
            float pp = __builtin_amdgcn_exp2f((fe_s[i] - mm) * LOG2E);
            sm_s[i] = pp; ss += pp;
        }
        float inv = 1.0f / ss;
        for (int i = 0; i < FFEAT; ++i) sm_s[i] *= inv;
    }
    __syncthreads();
    for (int i = tid; i < 4096; i += 256) scr[i] = fav[i];
    __syncthreads();
    {
        float acc = 0.f;
        for (int i = q4; i < FFEAT; i += 4) {
            float dot = fabv[c];
            #pragma unroll
            for (int jj = 0; jj < HDIM; ++jj) dot += emb_s[i][jj] * scr[jj * HDIM + c];
            acc += sm_s[i] * dot;
        }
        ((float*)ctx_s)[q4 * 64 + c] = acc;
    }
    __syncthreads();
    if (tid < HDIM) {
        v_s[tid] = ((float*)ctx_s)[tid] + ((float*)ctx_s)[64 + tid] +
                   ((float*)ctx_s)[128 + tid] + ((float*)ctx_s)[192 + tid];
    }
    __syncthreads();

    for (int i = tid; i < 4096; i += 256) scr[i] = o0w[i];
    __syncthreads();
    if (tid < HDIM) {
        float acc = o0b[tid];
        #pragma unroll
        for (int jj = 0; jj < HDIM; ++jj) acc += v_s[jj] * scr[jj * HDIM + tid];
        ((float*)ctx_s)[512 + tid] = fmaxf(acc, 0.f);
    }
    __syncthreads();
    if (tid == 0) {
        float acc = o1b[0];
        #pragma unroll
        for (int jj = 0; jj < HDIM; ++jj) acc += ((float*)ctx_s)[512 + jj] * o1w[jj];
        out[b] = fast_sigmoid(acc);
    }
}

__global__ void ws_report_kernel(float* out, int n, float ws_mib) {
    int i = blockIdx.x * blockDim.x + threadIdx.x;
    if (i < n) out[i] = ws_mib;
}

extern "C" void kernel_launch(void* const* d_in, const int* in_sizes, int n_in,
                              void* d_out, int out_size, void* d_ws, size_t ws_size,
                              hipStream_t stream)
{
    const float* x     = (const float*)d_in[0];
    const float* w_ih  = (const float*)d_in[1];
    const float* w_hh  = (const float*)d_in[2];
    const float* b_ih  = (const float*)d_in[3];
    const float* b_hh  = (const float*)d_in[4];
    const float* attWt = (const float*)d_in[5];
    const float* attWx = (const float*)d_in[6];
    const float* attRt = (const float*)d_in[7];
    const float* wq    = (const float*)d_in[8];
    const float* bq    = (const float*)d_in[9];
    const float* wk    = (const float*)d_in[10];
    const float* bk    = (const float*)d_in[11];
    const float* wv    = (const float*)d_in[12];
    const float* bv    = (const float*)d_in[13];
    const float* wo    = (const float*)d_in[14];
    const float* bo    = (const float*)d_in[15];
    const float* w1    = (const float*)d_in[16];
    const float* b1    = (const float*)d_in[17];
    const float* w2    = (const float*)d_in[18];
    const float* b2    = (const float*)d_in[19];
    const float* faq   = (const float*)d_in[20];
    const float* fabq  = (const float*)d_in[21];
    const float* fak   = (const float*)d_in[22];
    const float* fabk  = (const float*)d_in[23];
    const float* fav   = (const float*)d_in[24];
    const float* fabv  = (const float*)d_in[25];
    const float* o0w   = (const float*)d_in[26];
    const float* o0b   = (const float*)d_in[27];
    const float* o1w   = (const float*)d_in[28];
    const float* o1b   = (const float*)d_in[29];
    float* out = (float*)d_out;

    const size_t emb_bytes = (size_t)BBATCH * FFEAT * HDIM * 4;

    const int chunk_opts[6] = {76, 38, 19, 4, 2, 1};
    int FC = 0;
    for (int i = 0; i < 6; ++i) {
        size_t hs_b = (size_t)chunk_opts[i] * BBATCH * TT * HDIM * 2;
        if (emb_bytes + hs_b <= ws_size) { FC = chunk_opts[i]; break; }
    }
    if (FC == 0) {
        ws_report_kernel<<<dim3((out_size + 255) / 256), dim3(256), 0, stream>>>(
            out, out_size, (float)((double)ws_size / (1024.0 * 1024.0)));
        return;
    }

    float* emb = (float*)d_ws;
    __hip_bfloat16* hs = (__hip_bfloat16*)((char*)d_ws + emb_bytes);

    for (int f0 = 0; f0 < FFEAT; f0 += FC) {
        int fc = (FFEAT - f0 < FC) ? (FFEAT - f0) : FC;
        gru_mfma_kernel<<<dim3(4, fc), dim3(512), 0, stream>>>(
            x, w_ih, w_hh, b_ih, b_hh, f0, hs);
        attn_kernel<<<dim3(BBATCH, fc), dim3(128), 0, stream>>>(
            hs, attWt, attWx, attRt, f0, emb);
    }
    tail_kernel<<<dim3(BBATCH), dim3(256), 0, stream>>>(
        emb, wq, bq, wk, bk, wv, bv, wo, bo, w1, b1, w2, b2,
        faq, fabq, fak, fabk, fav, fabv, o0w, o0b, o1w, o1b, out);
}

// Round 4
// 694.075 us; speedup vs baseline: 1.9692x; 1.1477x over previous
//
#include <hip/hip_runtime.h>
#include <hip/hip_bf16.h>
#include <cstdint>
#include <cstddef>

#define TT 128
#define BBATCH 256
#define FFEAT 76
#define HDIM 64
#define NHEAD 4
#define DKH 16
#define DFF1 256
#define AH1 8
#define NROWS (BBATCH * FFEAT)   // 19456, divisible by 64

#define LOG2E 1.4426950408889634f

typedef __attribute__((ext_vector_type(8))) short bf16x8;
typedef __attribute__((ext_vector_type(4))) float f32x4;

__device__ __forceinline__ float fast_sigmoid(float v) {
    float p = __builtin_amdgcn_exp2f(-v * LOG2E);
    return __builtin_amdgcn_rcpf(1.0f + p);
}
__device__ __forceinline__ float fast_tanh(float v) {
    float p = __builtin_amdgcn_exp2f(v * (2.0f * LOG2E));
    return 1.0f - 2.0f * __builtin_amdgcn_rcpf(1.0f + p);
}
__device__ __forceinline__ short f2bf(float x) {
    __hip_bfloat16 h = __float2bfloat16(x);
    return *reinterpret_cast<short*>(&h);
}

// ---------------------------------------------------------------------------
// Kernel 1: MFMA GRU, double-buffered h in LDS -> ONE barrier per timestep.
// Block = (feature, 64-batch quarter), 512 thr = 8 waves.
// ---------------------------------------------------------------------------
__global__ __launch_bounds__(512, 2) void gru_mfma_kernel(
    const float* __restrict__ x, const float* __restrict__ w_ih,
    const float* __restrict__ w_hh, const float* __restrict__ b_ih,
    const float* __restrict__ b_hh, int f_base, __hip_bfloat16* __restrict__ hs)
{
    const int f_loc = blockIdx.y;
    const int f     = f_base + f_loc;
    const int b0    = blockIdx.x * 64;
    const int tid   = threadIdx.x;
    const int wave  = tid >> 6;
    const int lane  = tid & 63;
    const int col   = lane & 15;
    const int quad  = lane >> 4;
    const int ug    = wave & 3;
    const int mt0   = (wave >> 2) * 2;
    const int u     = ug * 16 + col;

    __shared__ __align__(16) short h_lds[2][64][72];   // double buffer
    __shared__ __align__(16) float x_lds[TT][64];

    for (int i = tid; i < TT * 64; i += 512) {
        int t = i >> 6, b = i & 63;
        x_lds[t][b] = x[(size_t)t * BBATCH * FFEAT + (size_t)(b0 + b) * FFEAT + f];
    }
    for (int i = tid; i < 64 * 72; i += 512) ((short*)h_lds[0])[i] = 0;

    bf16x8 bfr[3][2];
    {
        const float* whh_f = w_hh + (size_t)f * 192 * 64;
        #pragma unroll
        for (int gi = 0; gi < 3; ++gi) {
            const float* row = whh_f + (size_t)(gi * 64 + u) * 64;
            #pragma unroll
            for (int kq = 0; kq < 2; ++kq) {
                const float* src = row + kq * 32 + quad * 8;
                bf16x8 fr;
                #pragma unroll
                for (int j = 0; j < 8; ++j) fr[j] = f2bf(src[j]);
                bfr[gi][kq] = fr;
            }
        }
    }
    const float wihr  = w_ih[f*192 + u];
    const float wihz  = w_ih[f*192 + 64 + u];
    const float wihn  = w_ih[f*192 + 128 + u];
    const float brz_r = b_ih[f*192 + u]      + b_hh[f*192 + u];
    const float brz_z = b_ih[f*192 + 64 + u] + b_hh[f*192 + 64 + u];
    const float bih_n = b_ih[f*192 + 128 + u];
    const float bhh_n = b_hh[f*192 + 128 + u];

    float hprev[2][4] = {{0.f,0.f,0.f,0.f},{0.f,0.f,0.f,0.f}};
    __syncthreads();

    int p = 0;
    for (int t = 0; t < TT; ++t) {
        bf16x8 afr[2][2];
        #pragma unroll
        for (int mi = 0; mi < 2; ++mi)
            #pragma unroll
            for (int kq = 0; kq < 2; ++kq)
                afr[mi][kq] = *(const bf16x8*)&h_lds[p][(mt0+mi)*16 + col][kq*32 + quad*8];

        f32x4 acc[2][3];
        #pragma unroll
        for (int mi = 0; mi < 2; ++mi)
            #pragma unroll
            for (int gi = 0; gi < 3; ++gi) {
                f32x4 a = {0.f, 0.f, 0.f, 0.f};
                a = __builtin_amdgcn_mfma_f32_16x16x32_bf16(afr[mi][0], bfr[gi][0], a, 0, 0, 0);
                a = __builtin_amdgcn_mfma_f32_16x16x32_bf16(afr[mi][1], bfr[gi][1], a, 0, 0, 0);
                acc[mi][gi] = a;
            }

        #pragma unroll
        for (int mi = 0; mi < 2; ++mi) {
            const int brow = (mt0 + mi) * 16 + quad * 4;
            float4 xv = *(const float4*)&x_lds[t][brow];
            #pragma unroll
            for (int r = 0; r < 4; ++r) {
                float xb = (&xv.x)[r];
                float R  = acc[mi][0][r] + fmaf(xb, wihr, brz_r);
                float Z  = acc[mi][1][r] + fmaf(xb, wihz, brz_z);
                float NH = acc[mi][2][r] + bhh_n;
                float NX = fmaf(xb, wihn, bih_n);
                float rg = fast_sigmoid(R);
                float zg = fast_sigmoid(Z);
                float ng = fast_tanh(fmaf(rg, NH, NX));
                float hn = fmaf(zg, hprev[mi][r] - ng, ng);
                hprev[mi][r] = hn;
                short hb = f2bf(hn);
                h_lds[p^1][brow + r][u] = hb;
                hs[(((size_t)f_loc * BBATCH + b0 + brow + r) * TT + t) * HDIM + u] =
                    *reinterpret_cast<__hip_bfloat16*>(&hb);
            }
        }
        __syncthreads();   // writes to buf p^1 visible; everyone done reading buf p
        p ^= 1;
    }
}

// ---------------------------------------------------------------------------
// Kernel 2: per-(f,b) time attention (unchanged).
// ---------------------------------------------------------------------------
__global__ __launch_bounds__(128) void attn_kernel(
    const __hip_bfloat16* __restrict__ hs, const float* __restrict__ Wt,
    const float* __restrict__ Wx, const float* __restrict__ rate,
    int f_base, float* __restrict__ emb)
{
    const int b     = blockIdx.x;
    const int f_loc = blockIdx.y;
    const int f     = f_base + f_loc;
    const int tid   = threadIdx.x;

    __shared__ float h_s[TT][HDIM + 1];
    __shared__ float wx_s[HDIM][AH1];
    __shared__ float wt_s[HDIM][AH1];
    __shared__ float q_s[AH1];
    __shared__ float a_s[TT];
    __shared__ float redm[2], redp[2];
    __shared__ float partial_s[HDIM];

    for (int i = tid; i < HDIM * AH1; i += 128) {
        ((float*)wx_s)[i] = Wx[(size_t)f * HDIM * AH1 + i];
        ((float*)wt_s)[i] = Wt[(size_t)f * HDIM * AH1 + i];
    }

    float hreg[HDIM];
    {
        const __hip_bfloat16* src = hs + (((size_t)f_loc * BBATCH + b) * TT + tid) * HDIM;
        #pragma unroll
        for (int c = 0; c < 8; ++c) {
            uint4 u4 = ((const uint4*)src)[c];
            unsigned vals[4] = {u4.x, u4.y, u4.z, u4.w};
            #pragma unroll
            for (int pp = 0; pp < 4; ++pp) {
                hreg[c*8 + 2*pp]     = __uint_as_float(vals[pp] << 16);
                hreg[c*8 + 2*pp + 1] = __uint_as_float(vals[pp] & 0xffff0000u);
            }
        }
        #pragma unroll
        for (int j = 0; j < HDIM; ++j) h_s[tid][j] = hreg[j];
    }
    __syncthreads();

    if (tid < AH1) {
        float acc = 0.f;
        #pragma unroll
        for (int j = 0; j < HDIM; ++j) acc += h_s[TT-1][j] * wt_s[j][tid];
        q_s[tid] = acc;
    }
    __syncthreads();

    float k[AH1];
    #pragma unroll
    for (int a = 0; a < AH1; ++a) k[a] = 0.f;
    #pragma unroll
    for (int j = 0; j < HDIM; ++j) {
        float hv = hreg[j];
        #pragma unroll
        for (int a = 0; a < AH1; ++a) k[a] = fmaf(hv, wx_s[j][a], k[a]);
    }
    float dp = 0.f;
    #pragma unroll
    for (int a = 0; a < AH1; ++a) dp += k[a] * q_s[a];

    float sig   = fast_sigmoid(dp);
    float rs    = fast_sigmoid(rate[f]);
    float decay = (float)(TT - tid);
    float denom = rs * (__logf(2.72f + (1.0f - sig)) * decay);
    float e = fmaxf(sig / denom, 0.0f);

    float m = e;
    #pragma unroll
    for (int off = 32; off > 0; off >>= 1) m = fmaxf(m, __shfl_xor(m, off, 64));
    if ((tid & 63) == 0) redm[tid >> 6] = m;
    __syncthreads();
    m = fmaxf(redm[0], redm[1]);
    float pr = __builtin_amdgcn_exp2f((e - m) * LOG2E);
    float s = pr;
    #pragma unroll
    for (int off = 32; off > 0; off >>= 1) s += __shfl_xor(s, off, 64);
    if ((tid & 63) == 0) redp[tid >> 6] = s;
    __syncthreads();
    s = redp[0] + redp[1];
    a_s[tid] = pr / s;
    __syncthreads();

    const int j    = tid & 63;
    const int half = tid >> 6;
    float acc = 0.f;
    const int t0 = half * 64;
    #pragma unroll 8
    for (int t2 = t0; t2 < t0 + 64; ++t2)
        acc = fmaf(a_s[t2], h_s[t2][j], acc);
    if (half) partial_s[j] = acc;
    __syncthreads();
    if (!half) emb[((size_t)b * FFEAT + f) * HDIM + j] = acc + partial_s[j];
}

// ---------------------------------------------------------------------------
// Generic tiled GEMM: Y[z] = act(X @ W[z] + B[z]) (+ R). 64x64 tiles.
// grid = (M/64, Nfull/64, nmat). Block 256 thr, each thread 4x4 outputs.
// ---------------------------------------------------------------------------
struct GemmP {
    const float* X;
    const float* W[3];
    const float* B[3];
    const float* R;       // residual (nullptr if none), layout [M][Nfull]
    float* Y[3];
    int K;
    int Nfull;
    int act;              // 1 = relu before residual-add
};

__global__ __launch_bounds__(256) void gemm_kernel(GemmP A)
{
    __shared__ float xs[64][65];    // [row][k], scalar access, conflict-free
    __shared__ float ws[64][68];    // [k][col], float4 access, 16B-aligned rows

    const int tid = threadIdx.x;
    const int tx  = tid & 15;       // col group
    const int ty  = tid >> 4;       // row group
    const int m0  = blockIdx.x * 64;
    const int n0  = blockIdx.y * 64;
    const int z   = blockIdx.z;

    const float* W = A.W[z];
    const float* Bv = A.B[z];
    float* Y = A.Y[z];
    const int K = A.K, Nfull = A.Nfull;

    float acc[4][4];
    #pragma unroll
    for (int i = 0; i < 4; ++i)
        #pragma unroll
        for (int j = 0; j < 4; ++j) acc[i][j] = 0.f;

    for (int kc = 0; kc < K; kc += 64) {
        for (int s = tid; s < 1024; s += 256) {
            int row = s >> 4, c4 = s & 15;
            float4 xv = *(const float4*)&A.X[(size_t)(m0 + row) * K + kc + 4*c4];
            xs[row][4*c4+0] = xv.x; xs[row][4*c4+1] = xv.y;
            xs[row][4*c4+2] = xv.z; xs[row][4*c4+3] = xv.w;
            float4 wv = *(const float4*)&W[(size_t)(kc + row) * Nfull + n0 + 4*c4];
            *(float4*)&ws[row][4*c4] = wv;
        }
        __syncthreads();
        #pragma unroll 16
        for (int k = 0; k < 64; ++k) {
            float a0 = xs[4*ty+0][k], a1 = xs[4*ty+1][k];
            float a2 = xs[4*ty+2][k], a3 = xs[4*ty+3][k];
            float4 wv = *(const float4*)&ws[k][4*tx];
            #pragma unroll
            for (int j = 0; j < 4; ++j) {
                float wj = (&wv.x)[j];
                acc[0][j] = fmaf(a0, wj, acc[0][j]);
                acc[1][j] = fmaf(a1, wj, acc[1][j]);
                acc[2][j] = fmaf(a2, wj, acc[2][j]);
                acc[3][j] = fmaf(a3, wj, acc[3][j]);
            }
        }
        __syncthreads();
    }

    float4 bias = *(const float4*)&Bv[n0 + 4*tx];
    #pragma unroll
    for (int i = 0; i < 4; ++i) {
        int row = m0 + 4*ty + i;
        float4 v;
        v.x = acc[i][0] + bias.x; v.y = acc[i][1] + bias.y;
        v.z = acc[i][2] + bias.z; v.w = acc[i][3] + bias.w;
        if (A.act) {
            v.x = fmaxf(v.x, 0.f); v.y = fmaxf(v.y, 0.f);
            v.z = fmaxf(v.z, 0.f); v.w = fmaxf(v.w, 0.f);
        }
        if (A.R) {
            float4 r4 = *(const float4*)&A.R[(size_t)row * Nfull + n0 + 4*tx];
            v.x += r4.x; v.y += r4.y; v.z += r4.z; v.w += r4.w;
        }
        *(float4*)&Y[(size_t)row * Nfull + n0 + 4*tx] = v;
    }
}

// ---------------------------------------------------------------------------
// MHA core: per (b, head) block computes softmax(QK^T/4)V over F=76 features.
// ---------------------------------------------------------------------------
__global__ __launch_bounds__(256) void mha_core_kernel(
    const float* __restrict__ q, const float* __restrict__ k,
    const float* __restrict__ v, float* __restrict__ ctx)
{
    const int b  = blockIdx.x;
    const int hh = blockIdx.y;
    const int tid = threadIdx.x;

    __shared__ float qs[FFEAT][17];
    __shared__ float ks[FFEAT][17];
    __shared__ float vs[FFEAT][17];
    __shared__ float ps[FFEAT][77];

    for (int idx = tid; idx < FFEAT * DKH; idx += 256) {
        int i = idx >> 4, c = idx & 15;
        size_t g = ((size_t)b * FFEAT + i) * HDIM + hh * DKH + c;
        qs[i][c] = q[g]; ks[i][c] = k[g]; vs[i][c] = v[g];
    }
    __syncthreads();

    // scores
    for (int idx = tid; idx < FFEAT * FFEAT; idx += 256) {
        int i = idx / FFEAT, j = idx % FFEAT;
        float acc = 0.f;
        #pragma unroll
        for (int c = 0; c < DKH; ++c) acc = fmaf(qs[i][c], ks[j][c], acc);
        ps[i][j] = acc * 0.25f;
    }
    __syncthreads();

    // row softmax (thread per row)
    if (tid < FFEAT) {
        float mm = ps[tid][0];
        #pragma unroll 4
        for (int j = 1; j < FFEAT; ++j) mm = fmaxf(mm, ps[tid][j]);
        float ss = 0.f;
        #pragma unroll 4
        for (int j = 0; j < FFEAT; ++j) {
            float pv = __builtin_amdgcn_exp2f((ps[tid][j] - mm) * LOG2E);
            ps[tid][j] = pv; ss += pv;
        }
        float inv = 1.0f / ss;
        #pragma unroll 4
        for (int j = 0; j < FFEAT; ++j) ps[tid][j] *= inv;
    }
    __syncthreads();

    // ctx
    for (int idx = tid; idx < FFEAT * DKH; idx += 256) {
        int i = idx >> 4, c = idx & 15;
        float acc = 0.f;
        #pragma unroll 4
        for (int j = 0; j < FFEAT; ++j) acc = fmaf(ps[i][j], vs[j][c], acc);
        ctx[((size_t)b * FFEAT + i) * HDIM + hh * DKH + c] = acc;
    }
}

// ---------------------------------------------------------------------------
// Final attention + output head, one block (128 thr) per batch element.
// ---------------------------------------------------------------------------
__global__ __launch_bounds__(128) void final_kernel(
    const float* __restrict__ ctx3, const float* __restrict__ fk,
    const float* __restrict__ fv,
    const float* __restrict__ faq, const float* __restrict__ fabq,
    const float* __restrict__ o0w, const float* __restrict__ o0b,
    const float* __restrict__ o1w, const float* __restrict__ o1b,
    float* __restrict__ out)
{
    const int b = blockIdx.x;
    const int tid = threadIdx.x;

    __shared__ float last[HDIM];
    __shared__ float fqs[HDIM];
    __shared__ float sm[FFEAT];
    __shared__ float vv[HDIM];
    __shared__ float hh[HDIM];
    __shared__ float redm[2], redp[2];

    if (tid < HDIM) last[tid] = ctx3[((size_t)b * FFEAT + FFEAT - 1) * HDIM + tid];
    __syncthreads();
    if (tid < HDIM) {
        float acc = fabq[tid];
        #pragma unroll 8
        for (int j = 0; j < HDIM; ++j) acc = fmaf(last[j], faq[j * HDIM + tid], acc);
        fqs[tid] = acc;
    }
    __syncthreads();

    float e = -3.0e38f;
    if (tid < FFEAT) {
        const float4* kr = (const float4*)&fk[((size_t)b * FFEAT + tid) * HDIM];
        float acc = 0.f;
        #pragma unroll
        for (int c4 = 0; c4 < 16; ++c4) {
            float4 kv = kr[c4];
            acc = fmaf(kv.x, fqs[4*c4+0], acc);
            acc = fmaf(kv.y, fqs[4*c4+1], acc);
            acc = fmaf(kv.z, fqs[4*c4+2], acc);
            acc = fmaf(kv.w, fqs[4*c4+3], acc);
        }
        e = acc;
    }
    float m = e;
    #pragma unroll
    for (int off = 32; off > 0; off >>= 1) m = fmaxf(m, __shfl_xor(m, off, 64));
    if ((tid & 63) == 0) redm[tid >> 6] = m;
    __syncthreads();
    m = fmaxf(redm[0], redm[1]);
    float p = (tid < FFEAT) ? __builtin_amdgcn_exp2f((e - m) * LOG2E) : 0.f;
    float s = p;
    #pragma unroll
    for (int off = 32; off > 0; off >>= 1) s += __shfl_xor(s, off, 64);
    if ((tid & 63) == 0) redp[tid >> 6] = s;
    __syncthreads();
    s = redp[0] + redp[1];
    if (tid < FFEAT) sm[tid] = p / s;
    __syncthreads();

    if (tid < HDIM) {
        float acc = 0.f;
        for (int ff = 0; ff < FFEAT; ++ff)
            acc = fmaf(sm[ff], fv[((size_t)b * FFEAT + ff) * HDIM + tid], acc);
        vv[tid] = acc;
    }
    __syncthreads();
    if (tid < HDIM) {
        float acc = o0b[tid];
        #pragma unroll 8
        for (int j = 0; j < HDIM; ++j) acc = fmaf(vv[j], o0w[j * HDIM + tid], acc);
        hh[tid] = fmaxf(acc, 0.f);
    }
    __syncthreads();
    if (tid < 64) {
        float t = hh[tid] * o1w[tid];
        #pragma unroll
        for (int off = 32; off > 0; off >>= 1) t += __shfl_xor(t, off, 64);
        if (tid == 0) out[b] = fast_sigmoid(t + o1b[0]);
    }
}

__global__ void ws_report_kernel(float* out, int n, float ws_mib) {
    int i = blockIdx.x * blockDim.x + threadIdx.x;
    if (i < n) out[i] = ws_mib;
}

extern "C" void kernel_launch(void* const* d_in, const int* in_sizes, int n_in,
                              void* d_out, int out_size, void* d_ws, size_t ws_size,
                              hipStream_t stream)
{
    const float* x     = (const float*)d_in[0];
    const float* w_ih  = (const float*)d_in[1];
    const float* w_hh  = (const float*)d_in[2];
    const float* b_ih  = (const float*)d_in[3];
    const float* b_hh  = (const float*)d_in[4];
    const float* attWt = (const float*)d_in[5];
    const float* attWx = (const float*)d_in[6];
    const float* attRt = (const float*)d_in[7];
    const float* wq    = (const float*)d_in[8];
    const float* bq    = (const float*)d_in[9];
    const float* wk    = (const float*)d_in[10];
    const float* bk    = (const float*)d_in[11];
    const float* wv    = (const float*)d_in[12];
    const float* bv    = (const float*)d_in[13];
    const float* wo    = (const float*)d_in[14];
    const float* bo    = (const float*)d_in[15];
    const float* w1    = (const float*)d_in[16];
    const float* b1    = (const float*)d_in[17];
    const float* w2    = (const float*)d_in[18];
    const float* b2    = (const float*)d_in[19];
    const float* faq   = (const float*)d_in[20];
    const float* fabq  = (const float*)d_in[21];
    const float* fak   = (const float*)d_in[22];
    const float* fabk  = (const float*)d_in[23];
    const float* fav   = (const float*)d_in[24];
    const float* fabv  = (const float*)d_in[25];
    const float* o0w   = (const float*)d_in[26];
    const float* o0b   = (const float*)d_in[27];
    const float* o1w   = (const float*)d_in[28];
    const float* o1b   = (const float*)d_in[29];
    float* out = (float*)d_out;

    const size_t emb_bytes  = (size_t)NROWS * HDIM * 4;        // 4.75 MiB
    const size_t R64        = (size_t)NROWS * HDIM;            // elems
    const size_t tail_bytes = 12 * R64 * 4;                    // ~57 MiB

    const int chunk_opts[6] = {76, 38, 19, 4, 2, 1};
    int FC = 0;
    for (int i = 0; i < 6; ++i) {
        size_t hs_b = (size_t)chunk_opts[i] * BBATCH * TT * HDIM * 2;
        size_t scratch = hs_b > tail_bytes ? hs_b : tail_bytes;
        if (emb_bytes + scratch <= ws_size) { FC = chunk_opts[i]; break; }
    }
    if (FC == 0) {
        ws_report_kernel<<<dim3((out_size + 255) / 256), dim3(256), 0, stream>>>(
            out, out_size, (float)((double)ws_size / (1024.0 * 1024.0)));
        return;
    }

    float* emb = (float*)d_ws;
    char*  scratch = (char*)d_ws + emb_bytes;
    __hip_bfloat16* hs = (__hip_bfloat16*)scratch;

    // ---- GRU + time attention, chunked over features ----
    for (int f0 = 0; f0 < FFEAT; f0 += FC) {
        int fc = (FFEAT - f0 < FC) ? (FFEAT - f0) : FC;
        gru_mfma_kernel<<<dim3(4, fc), dim3(512), 0, stream>>>(
            x, w_ih, w_hh, b_ih, b_hh, f0, hs);
        attn_kernel<<<dim3(BBATCH, fc), dim3(128), 0, stream>>>(
            hs, attWt, attWx, attRt, f0, emb);
    }

    // ---- tail scratch aliases hs (hs fully consumed above) ----
    float* ts   = (float*)scratch;
    float* q    = ts;
    float* k    = ts + 1*R64;
    float* v    = ts + 2*R64;
    float* ctx  = ts + 3*R64;
    float* ctx2 = ts + 4*R64;
    float* hid  = ts + 5*R64;   // 4*R64 (N=256)
    float* ctx3 = ts + 9*R64;
    float* fk   = ts + 10*R64;
    float* fv   = ts + 11*R64;

    const int MB = NROWS / 64;  // 304

    // QKV projections
    {
        GemmP A = { emb, {wq, wk, wv}, {bq, bk, bv}, nullptr, {q, k, v}, 64, 64, 0 };
        gemm_kernel<<<dim3(MB, 1, 3), dim3(256), 0, stream>>>(A);
    }
    // MHA core
    mha_core_kernel<<<dim3(BBATCH, NHEAD), dim3(256), 0, stream>>>(q, k, v, ctx);
    // out-proj + residual
    {
        GemmP A = { ctx, {wo, nullptr, nullptr}, {bo, nullptr, nullptr}, emb,
                    {ctx2, nullptr, nullptr}, 64, 64, 0 };
        gemm_kernel<<<dim3(MB, 1, 1), dim3(256), 0, stream>>>(A);
    }
    // FFN1 (relu)
    {
        GemmP A = { ctx2, {w1, nullptr, nullptr}, {b1, nullptr, nullptr}, nullptr,
                    {hid, nullptr, nullptr}, 64, 256, 1 };
        gemm_kernel<<<dim3(MB, 4, 1), dim3(256), 0, stream>>>(A);
    }
    // FFN2 + residual
    {
        GemmP A = { hid, {w2, nullptr, nullptr}, {b2, nullptr, nullptr}, ctx2,
                    {ctx3, nullptr, nullptr}, 256, 64, 0 };
        gemm_kernel<<<dim3(MB, 1, 1), dim3(256), 0, stream>>>(A);
    }
    // fk / fv
    {
        GemmP A = { ctx3, {fak, fav, nullptr}, {fabk, fabv, nullptr}, nullptr,
                    {fk, fv, nullptr}, 64, 64, 0 };
        gemm_kernel<<<dim3(MB, 1, 2), dim3(256), 0, stream>>>(A);
    }
    // final attention + head
    final_kernel<<<dim3(BBATCH), dim3(128), 0, stream>>>(
        ctx3, fk, fv, faq, fabq, o0w, o0b, o1w, o1b, out);
}

// Round 5
// 690.945 us; speedup vs baseline: 1.9781x; 1.0045x over previous
//
#include <hip/hip_runtime.h>
#include <hip/hip_bf16.h>
#include <cstdint>
#include <cstddef>

#define TT 128
#define BBATCH 256
#define FFEAT 76
#define HDIM 64
#define NHEAD 4
#define DKH 16
#define DFF1 256
#define AH1 8
#define NROWS (BBATCH * FFEAT)   // 19456

#define LOG2E 1.4426950408889634f

typedef __attribute__((ext_vector_type(8))) short bf16x8;
typedef __attribute__((ext_vector_type(4))) float f32x4;

__device__ __forceinline__ float fast_sigmoid(float v) {
    float p = __builtin_amdgcn_exp2f(-v * LOG2E);
    return __builtin_amdgcn_rcpf(1.0f + p);
}
__device__ __forceinline__ float fast_tanh(float v) {
    float p = __builtin_amdgcn_exp2f(v * (2.0f * LOG2E));
    return 1.0f - 2.0f * __builtin_amdgcn_rcpf(1.0f + p);
}
__device__ __forceinline__ short f2bf(float x) {
    __hip_bfloat16 h = __float2bfloat16(x);
    return *reinterpret_cast<short*>(&h);
}
__device__ __forceinline__ float bf2f(unsigned short s) {
    return __uint_as_float(((unsigned)s) << 16);
}

// ---------------------------------------------------------------------------
// Kernel 1: barrier-free GRU scan. Block = 256 thr = 4 independent waves;
// each wave owns 16 batches x all 64 units (M=16, N=192 -> 12 N-tiles,
// 24 MFMAs/wave/t). h exchange is wave-internal LDS (in-order, no barrier).
// Writes hs bf16 [f_loc][t][256][64] (coalesced from A-frags) and
// wtil[b][f][64] = Wx * (Wt^T h_127) for the attention dp collapse.
// ---------------------------------------------------------------------------
__global__ __launch_bounds__(256) void gru_scan_kernel(
    const float* __restrict__ x, const float* __restrict__ w_ih,
    const float* __restrict__ w_hh, const float* __restrict__ b_ih,
    const float* __restrict__ b_hh, const float* __restrict__ Wt,
    const float* __restrict__ Wx, int f_base,
    __hip_bfloat16* __restrict__ hs, float* __restrict__ wtil)
{
    const int f_loc = blockIdx.y;
    const int f     = f_base + f_loc;
    const int bblk  = blockIdx.x * 64;
    const int tid   = threadIdx.x;
    const int wave  = tid >> 6;
    const int lane  = tid & 63;
    const int c     = lane & 15;
    const int q     = lane >> 4;
    const int b0    = bblk + wave * 16;     // this wave's 16 batches

    __shared__ float x_lds[TT][64];         // 32 KB [t][local b]
    __shared__ float wt_s[64][8];           // 2 KB
    __shared__ float wx_s[64][8];           // 2 KB
    __shared__ short hx[4][16][72];         // 9 KB, per-wave h exchange
    __shared__ float q_s[4][16][8];         // 2 KB

    for (int i = tid; i < TT * 64; i += 256) {
        int t = i >> 6, b = i & 63;
        x_lds[t][b] = x[((size_t)t * BBATCH + bblk + b) * FFEAT + f];
    }
    for (int i = tid; i < 512; i += 256) {
        ((float*)wt_s)[i] = Wt[(size_t)f * 512 + i];
        ((float*)wx_s)[i] = Wx[(size_t)f * 512 + i];
    }
    for (int i = lane; i < 16 * 72; i += 64) ((short*)hx[wave])[i] = 0;
    __syncthreads();   // the ONLY block barrier

    // B-fragments: 12 N-tiles x 2 K-halves, resident all loop (96 VGPRs)
    bf16x8 bfr[12][2];
    {
        const float* whh_f = w_hh + (size_t)f * 192 * 64;
        #pragma unroll
        for (int nt = 0; nt < 12; ++nt) {
            const float* row = whh_f + (size_t)(nt * 16 + c) * 64;
            #pragma unroll
            for (int kq = 0; kq < 2; ++kq) {
                bf16x8 fr;
                #pragma unroll
                for (int j = 0; j < 8; ++j) fr[j] = f2bf(row[kq * 32 + q * 8 + j]);
                bfr[nt][kq] = fr;
            }
        }
    }
    // per-lane gate constants: unit u = g*16 + c, g = 0..3
    float wihr[4], wihz[4], wihn[4], bR[4], bZ[4], bNX[4], bNH[4];
    #pragma unroll
    for (int g = 0; g < 4; ++g) {
        int u = g * 16 + c;
        wihr[g] = w_ih[f*192 + u];
        wihz[g] = w_ih[f*192 + 64 + u];
        wihn[g] = w_ih[f*192 + 128 + u];
        bR[g]  = b_ih[f*192 + u]      + b_hh[f*192 + u];
        bZ[g]  = b_ih[f*192 + 64 + u] + b_hh[f*192 + 64 + u];
        bNX[g] = b_ih[f*192 + 128 + u];
        bNH[g] = b_hh[f*192 + 128 + u];
    }

    float hprev[4][4];
    #pragma unroll
    for (int g = 0; g < 4; ++g)
        #pragma unroll
        for (int r = 0; r < 4; ++r) hprev[g][r] = 0.f;

    short* hs_s = (short*)hs + (size_t)f_loc * TT * BBATCH * HDIM;

    for (int t = 0; t < TT; ++t) {
        // A-frags = h_{t-1}[b=c][k=q*8..] ; also the coalesced store image
        bf16x8 a0 = *(const bf16x8*)&hx[wave][c][q * 8];
        bf16x8 a1 = *(const bf16x8*)&hx[wave][c][32 + q * 8];
        if (t > 0) {
            short* dst = hs_s + ((size_t)(t - 1) * BBATCH + b0 + c) * HDIM + q * 8;
            *(bf16x8*)dst = a0;
            *(bf16x8*)(dst + 32) = a1;
        }

        f32x4 acc[12];
        #pragma unroll
        for (int g = 0; g < 4; ++g) {
            acc[g]     = f32x4{bR[g],  bR[g],  bR[g],  bR[g]};
            acc[g + 4] = f32x4{bZ[g],  bZ[g],  bZ[g],  bZ[g]};
            acc[g + 8] = f32x4{bNH[g], bNH[g], bNH[g], bNH[g]};
        }
        #pragma unroll
        for (int nt = 0; nt < 12; ++nt) {
            acc[nt] = __builtin_amdgcn_mfma_f32_16x16x32_bf16(a0, bfr[nt][0], acc[nt], 0, 0, 0);
            acc[nt] = __builtin_amdgcn_mfma_f32_16x16x32_bf16(a1, bfr[nt][1], acc[nt], 0, 0, 0);
        }

        float4 xv = *(const float4*)&x_lds[t][wave * 16 + q * 4];
        #pragma unroll
        for (int g = 0; g < 4; ++g) {
            #pragma unroll
            for (int r = 0; r < 4; ++r) {
                float xb = (&xv.x)[r];
                float R  = fmaf(xb, wihr[g], acc[g][r]);
                float Z  = fmaf(xb, wihz[g], acc[g + 4][r]);
                float NX = fmaf(xb, wihn[g], bNX[g]);
                float rg = fast_sigmoid(R);
                float zg = fast_sigmoid(Z);
                float ng = fast_tanh(fmaf(rg, acc[g + 8][r], NX));
                float hn = fmaf(zg, hprev[g][r] - ng, ng);
                hprev[g][r] = hn;
                hx[wave][q * 4 + r][g * 16 + c] = f2bf(hn);
            }
        }
        // no barrier: same-wave LDS RAW ordered by hardware waitcnts
    }
    // store h_{T-1}
    {
        bf16x8 a0 = *(const bf16x8*)&hx[wave][c][q * 8];
        bf16x8 a1 = *(const bf16x8*)&hx[wave][c][32 + q * 8];
        short* dst = hs_s + ((size_t)(TT - 1) * BBATCH + b0 + c) * HDIM + q * 8;
        *(bf16x8*)dst = a0;
        *(bf16x8*)(dst + 32) = a1;
    }

    // q[b][a] = Wt^T h_127 : 128 roles, 2 per lane (wave-local)
    #pragma unroll
    for (int rr = 0; rr < 2; ++rr) {
        int role = rr * 64 + lane;
        int b = role >> 3, a = role & 7;
        float s = 0.f;
        #pragma unroll 8
        for (int j = 0; j < 64; ++j)
            s = fmaf(bf2f((unsigned short)hx[wave][b][j]), wt_s[j][a], s);
        q_s[wave][b][a] = s;
    }
    // wtilde[b][j] = sum_a Wx[j][a] * q[b][a]  (dp_t = h_t . wtilde)
    {
        int b = lane >> 2, jb = (lane & 3) * 16;
        float qreg[8];
        #pragma unroll
        for (int a = 0; a < 8; ++a) qreg[a] = q_s[wave][b][a];
        float* wt_out = wtil + ((size_t)(b0 + b) * FFEAT + f) * HDIM + jb;
        #pragma unroll
        for (int j4 = 0; j4 < 4; ++j4) {
            float4 v;
            #pragma unroll
            for (int jj = 0; jj < 4; ++jj) {
                int j = jb + j4 * 4 + jj;
                float s = 0.f;
                #pragma unroll
                for (int a = 0; a < 8; ++a) s = fmaf(wx_s[j][a], qreg[a], s);
                (&v.x)[jj] = s;
            }
            *(float4*)&wt_out[j4 * 4] = v;
        }
    }
}

// ---------------------------------------------------------------------------
// Kernel 2: time attention from collapsed projection. One wave per (b, f):
// dp_t = h_t . wtilde (one hs read), softmax over T, weighted sum (L1-hot
// re-read), write emb[b][f][:].
// ---------------------------------------------------------------------------
__global__ __launch_bounds__(64) void attn2_kernel(
    const __hip_bfloat16* __restrict__ hs, const float* __restrict__ wtil,
    const float* __restrict__ rate, int f_base, float* __restrict__ emb)
{
    const int b     = blockIdx.x;
    const int f_loc = blockIdx.y;
    const int f     = f_base + f_loc;
    const int lane  = threadIdx.x;

    __shared__ float a_s[TT];

    // wtilde into registers (all lanes read the same 256 B)
    float wreg[64];
    {
        const float4* src = (const float4*)(wtil + ((size_t)b * FFEAT + f) * HDIM);
        #pragma unroll
        for (int i = 0; i < 16; ++i) {
            float4 v = src[i];
            wreg[4*i+0] = v.x; wreg[4*i+1] = v.y; wreg[4*i+2] = v.z; wreg[4*i+3] = v.w;
        }
    }
    const float rs = fast_sigmoid(rate[f]);
    const short* hsp = (const short*)hs + (size_t)f_loc * TT * BBATCH * HDIM;

    // dp for t = lane and t = lane + 64
    float e[2];
    #pragma unroll
    for (int half = 0; half < 2; ++half) {
        int t = half * 64 + lane;
        const uint4* row = (const uint4*)(hsp + ((size_t)t * BBATCH + b) * HDIM);
        float dp = 0.f;
        #pragma unroll
        for (int c4 = 0; c4 < 8; ++c4) {
            uint4 u = row[c4];
            unsigned vals[4] = {u.x, u.y, u.z, u.w};
            #pragma unroll
            for (int p = 0; p < 4; ++p) {
                dp = fmaf(__uint_as_float(vals[p] << 16),        wreg[c4*8 + 2*p],     dp);
                dp = fmaf(__uint_as_float(vals[p] & 0xffff0000u), wreg[c4*8 + 2*p + 1], dp);
            }
        }
        float sig = fast_sigmoid(dp);
        float den = rs * (__logf(2.72f + (1.0f - sig)) * (float)(TT - t));
        e[half] = fmaxf(sig / den, 0.0f);
    }
    // softmax over 128 values (wave-wide shuffle)
    float m = fmaxf(e[0], e[1]);
    #pragma unroll
    for (int off = 32; off > 0; off >>= 1) m = fmaxf(m, __shfl_xor(m, off, 64));
    float p0 = __builtin_amdgcn_exp2f((e[0] - m) * LOG2E);
    float p1 = __builtin_amdgcn_exp2f((e[1] - m) * LOG2E);
    float s = p0 + p1;
    #pragma unroll
    for (int off = 32; off > 0; off >>= 1) s += __shfl_xor(s, off, 64);
    float inv = __builtin_amdgcn_rcpf(s);
    a_s[lane]      = p0 * inv;
    a_s[lane + 64] = p1 * inv;

    // weighted sum: lane = j; re-read is L1-hot (16 KB block working set)
    const int j = lane;
    float acc = 0.f;
    #pragma unroll 8
    for (int t = 0; t < TT; ++t) {
        unsigned short hv = *(const unsigned short*)(hsp + ((size_t)t * BBATCH + b) * HDIM + j);
        acc = fmaf(a_s[t], bf2f(hv), acc);
    }
    emb[((size_t)b * FFEAT + f) * HDIM + j] = acc;
}

// ---------------------------------------------------------------------------
// Tail (unchanged from round 4): tiled GEMM + MHA core + final head.
// ---------------------------------------------------------------------------
struct GemmP {
    const float* X;
    const float* W[3];
    const float* B[3];
    const float* R;
    float* Y[3];
    int K;
    int Nfull;
    int act;
};

__global__ __launch_bounds__(256) void gemm_kernel(GemmP A)
{
    __shared__ float xs[64][65];
    __shared__ float ws[64][68];

    const int tid = threadIdx.x;
    const int tx  = tid & 15;
    const int ty  = tid >> 4;
    const int m0  = blockIdx.x * 64;
    const int n0  = blockIdx.y * 64;
    const int z   = blockIdx.z;

    const float* W = A.W[z];
    const float* Bv = A.B[z];
    float* Y = A.Y[z];
    const int K = A.K, Nfull = A.Nfull;

    float acc[4][4];
    #pragma unroll
    for (int i = 0; i < 4; ++i)
        #pragma unroll
        for (int j = 0; j < 4; ++j) acc[i][j] = 0.f;

    for (int kc = 0; kc < K; kc += 64) {
        for (int s = tid; s < 1024; s += 256) {
            int row = s >> 4, c4 = s & 15;
            float4 xv = *(const float4*)&A.X[(size_t)(m0 + row) * K + kc + 4*c4];
            xs[row][4*c4+0] = xv.x; xs[row][4*c4+1] = xv.y;
            xs[row][4*c4+2] = xv.z; xs[row][4*c4+3] = xv.w;
            float4 wv = *(const float4*)&W[(size_t)(kc + row) * Nfull + n0 + 4*c4];
            *(float4*)&ws[row][4*c4] = wv;
        }
        __syncthreads();
        #pragma unroll 16
        for (int k = 0; k < 64; ++k) {
            float a0 = xs[4*ty+0][k], a1 = xs[4*ty+1][k];
            float a2 = xs[4*ty+2][k], a3 = xs[4*ty+3][k];
            float4 wv = *(const float4*)&ws[k][4*tx];
            #pragma unroll
            for (int j = 0; j < 4; ++j) {
                float wj = (&wv.x)[j];
                acc[0][j] = fmaf(a0, wj, acc[0][j]);
                acc[1][j] = fmaf(a1, wj, acc[1][j]);
                acc[2][j] = fmaf(a2, wj, acc[2][j]);
                acc[3][j] = fmaf(a3, wj, acc[3][j]);
            }
        }
        __syncthreads();
    }

    float4 bias = *(const float4*)&Bv[n0 + 4*tx];
    #pragma unroll
    for (int i = 0; i < 4; ++i) {
        int row = m0 + 4*ty + i;
        float4 v;
        v.x = acc[i][0] + bias.x; v.y = acc[i][1] + bias.y;
        v.z = acc[i][2] + bias.z; v.w = acc[i][3] + bias.w;
        if (A.act) {
            v.x = fmaxf(v.x, 0.f); v.y = fmaxf(v.y, 0.f);
            v.z = fmaxf(v.z, 0.f); v.w = fmaxf(v.w, 0.f);
        }
        if (A.R) {
            float4 r4 = *(const float4*)&A.R[(size_t)row * Nfull + n0 + 4*tx];
            v.x += r4.x; v.y += r4.y; v.z += r4.z; v.w += r4.w;
        }
        *(float4*)&Y[(size_t)row * Nfull + n0 + 4*tx] = v;
    }
}

__global__ __launch_bounds__(256) void mha_core_kernel(
    const float* __restrict__ q, const float* __restrict__ k,
    const float* __restrict__ v, float* __restrict__ ctx)
{
    const int b  = blockIdx.x;
    const int hh = blockIdx.y;
    const int tid = threadIdx.x;

    __shared__ float qs[FFEAT][17];
    __shared__ float ks[FFEAT][17];
    __shared__ float vs[FFEAT][17];
    __shared__ float ps[FFEAT][77];

    for (int idx = tid; idx < FFEAT * DKH; idx += 256) {
        int i = idx >> 4, c = idx & 15;
        size_t g = ((size_t)b * FFEAT + i) * HDIM + hh * DKH + c;
        qs[i][c] = q[g]; ks[i][c] = k[g]; vs[i][c] = v[g];
    }
    __syncthreads();

    for (int idx = tid; idx < FFEAT * FFEAT; idx += 256) {
        int i = idx / FFEAT, j = idx % FFEAT;
        float acc = 0.f;
        #pragma unroll
        for (int c = 0; c < DKH; ++c) acc = fmaf(qs[i][c], ks[j][c], acc);
        ps[i][j] = acc * 0.25f;
    }
    __syncthreads();

    if (tid < FFEAT) {
        float mm = ps[tid][0];
        #pragma unroll 4
        for (int j = 1; j < FFEAT; ++j) mm = fmaxf(mm, ps[tid][j]);
        float ss = 0.f;
        #pragma unroll 4
        for (int j = 0; j < FFEAT; ++j) {
            float pv = __builtin_amdgcn_exp2f((ps[tid][j] - mm) * LOG2E);
            ps[tid][j] = pv; ss += pv;
        }
        float inv = 1.0f / ss;
        #pragma unroll 4
        for (int j = 0; j < FFEAT; ++j) ps[tid][j] *= inv;
    }
    __syncthreads();

    for (int idx = tid; idx < FFEAT * DKH; idx += 256) {
        int i = idx >> 4, c = idx & 15;
        float acc = 0.f;
        #pragma unroll 4
        for (int j = 0; j < FFEAT; ++j) acc = fmaf(ps[i][j], vs[j][c], acc);
        ctx[((size_t)b * FFEAT + i) * HDIM + hh * DKH + c] = acc;
    }
}

__global__ __launch_bounds__(128) void final_kernel(
    const float* __restrict__ ctx3, const float* __restrict__ fk,
    const float* __restrict__ fv,
    const float* __restrict__ faq, const float* __restrict__ fabq,
    const float* __restrict__ o0w, const float* __restrict__ o0b,
    const float* __restrict__ o1w, const float* __restrict__ o1b,
    float* __restrict__ out)
{
    const int b = blockIdx.x;
    const int tid = threadIdx.x;

    __shared__ float last[HDIM];
    __shared__ float fqs[HDIM];
    __shared__ float sm[FFEAT];
    __shared__ float vv[HDIM];
    __shared__ float hh[HDIM];
    __shared__ float redm[2], redp[2];

    if (tid < HDIM) last[tid] = ctx3[((size_t)b * FFEAT + FFEAT - 1) * HDIM + tid];
    __syncthreads();
    if (tid < HDIM) {
        float acc = fabq[tid];
        #pragma unroll 8
        for (int j = 0; j < HDIM; ++j) acc = fmaf(last[j], faq[j * HDIM + tid], acc);
        fqs[tid] = acc;
    }
    __syncthreads();

    float e = -3.0e38f;
    if (tid < FFEAT) {
        const float4* kr = (const float4*)&fk[((size_t)b * FFEAT + tid) * HDIM];
        float acc = 0.f;
        #pragma unroll
        for (int c4 = 0; c4 < 16; ++c4) {
            float4 kv = kr[c4];
            acc = fmaf(kv.x, fqs[4*c4+0], acc);
            acc = fmaf(kv.y, fqs[4*c4+1], acc);
            acc = fmaf(kv.z, fqs[4*c4+2], acc);
            acc = fmaf(kv.w, fqs[4*c4+3], acc);
        }
        e = acc;
    }
    float m = e;
    #pragma unroll
    for (int off = 32; off > 0; off >>= 1) m = fmaxf(m, __shfl_xor(m, off, 64));
    if ((tid & 63) == 0) redm[tid >> 6] = m;
    __syncthreads();
    m = fmaxf(redm[0], redm[1]);
    float p = (tid < FFEAT) ? __builtin_amdgcn_exp2f((e - m) * LOG2E) : 0.f;
    float s = p;
    #pragma unroll
    for (int off = 32; off > 0; off >>= 1) s += __shfl_xor(s, off, 64);
    if ((tid & 63) == 0) redp[tid >> 6] = s;
    __syncthreads();
    s = redp[0] + redp[1];
    if (tid < FFEAT) sm[tid] = p / s;
    __syncthreads();

    if (tid < HDIM) {
        float acc = 0.f;
        for (int ff = 0; ff < FFEAT; ++ff)
            acc = fmaf(sm[ff], fv[((size_t)b * FFEAT + ff) * HDIM + tid], acc);
        vv[tid] = acc;
    }
    __syncthreads();
    if (tid < HDIM) {
        float acc = o0b[tid];
        #pragma unroll 8
        for (int j = 0; j < HDIM; ++j) acc = fmaf(vv[j], o0w[j * HDIM + tid], acc);
        hh[tid] = fmaxf(acc, 0.f);
    }
    __syncthreads();
    if (tid < 64) {
        float t = hh[tid] * o1w[tid];
        #pragma unroll
        for (int off = 32; off > 0; off >>= 1) t += __shfl_xor(t, off, 64);
        if (tid == 0) out[b] = fast_sigmoid(t + o1b[0]);
    }
}

__global__ void ws_report_kernel(float* out, int n, float ws_mib) {
    int i = blockIdx.x * blockDim.x + threadIdx.x;
    if (i < n) out[i] = ws_mib;
}

extern "C" void kernel_launch(void* const* d_in, const int* in_sizes, int n_in,
                              void* d_out, int out_size, void* d_ws, size_t ws_size,
                              hipStream_t stream)
{
    const float* x     = (const float*)d_in[0];
    const float* w_ih  = (const float*)d_in[1];
    const float* w_hh  = (const float*)d_in[2];
    const float* b_ih  = (const float*)d_in[3];
    const float* b_hh  = (const float*)d_in[4];
    const float* attWt = (const float*)d_in[5];
    const float* attWx = (const float*)d_in[6];
    const float* attRt = (const float*)d_in[7];
    const float* wq    = (const float*)d_in[8];
    const float* bq    = (const float*)d_in[9];
    const float* wk    = (const float*)d_in[10];
    const float* bk    = (const float*)d_in[11];
    const float* wv    = (const float*)d_in[12];
    const float* bv    = (const float*)d_in[13];
    const float* wo    = (const float*)d_in[14];
    const float* bo    = (const float*)d_in[15];
    const float* w1    = (const float*)d_in[16];
    const float* b1    = (const float*)d_in[17];
    const float* w2    = (const float*)d_in[18];
    const float* b2    = (const float*)d_in[19];
    const float* faq   = (const float*)d_in[20];
    const float* fabq  = (const float*)d_in[21];
    const float* fak   = (const float*)d_in[22];
    const float* fabk  = (const float*)d_in[23];
    const float* fav   = (const float*)d_in[24];
    const float* fabv  = (const float*)d_in[25];
    const float* o0w   = (const float*)d_in[26];
    const float* o0b   = (const float*)d_in[27];
    const float* o1w   = (const float*)d_in[28];
    const float* o1b   = (const float*)d_in[29];
    float* out = (float*)d_out;

    const size_t emb_bytes  = (size_t)NROWS * HDIM * 4;   // 4.98 MB
    const size_t wtil_bytes = (size_t)NROWS * HDIM * 4;   // 4.98 MB
    const size_t R64        = (size_t)NROWS * HDIM;
    const size_t tail_bytes = 12 * R64 * 4;               // ~57 MB

    const int chunk_opts[6] = {76, 38, 19, 4, 2, 1};
    int FC = 0;
    for (int i = 0; i < 6; ++i) {
        size_t hs_b = (size_t)chunk_opts[i] * BBATCH * TT * HDIM * 2;
        size_t scratch = hs_b > tail_bytes ? hs_b : tail_bytes;
        if (emb_bytes + wtil_bytes + scratch <= ws_size) { FC = chunk_opts[i]; break; }
    }
    if (FC == 0) {
        ws_report_kernel<<<dim3((out_size + 255) / 256), dim3(256), 0, stream>>>(
            out, out_size, (float)((double)ws_size / (1024.0 * 1024.0)));
        return;
    }

    float* emb  = (float*)d_ws;
    float* wtil = (float*)((char*)d_ws + emb_bytes);
    char*  scratch = (char*)d_ws + emb_bytes + wtil_bytes;
    __hip_bfloat16* hs = (__hip_bfloat16*)scratch;

    // ---- GRU scan + time attention, chunked over features ----
    for (int f0 = 0; f0 < FFEAT; f0 += FC) {
        int fc = (FFEAT - f0 < FC) ? (FFEAT - f0) : FC;
        gru_scan_kernel<<<dim3(4, fc), dim3(256), 0, stream>>>(
            x, w_ih, w_hh, b_ih, b_hh, attWt, attWx, f0, hs, wtil);
        attn2_kernel<<<dim3(BBATCH, fc), dim3(64), 0, stream>>>(
            hs, wtil, attRt, f0, emb);
    }

    // ---- tail scratch aliases hs ----
    float* ts   = (float*)scratch;
    float* q    = ts;
    float* k    = ts + 1*R64;
    float* v    = ts + 2*R64;
    float* ctx  = ts + 3*R64;
    float* ctx2 = ts + 4*R64;
    float* hid  = ts + 5*R64;
    float* ctx3 = ts + 9*R64;
    float* fk   = ts + 10*R64;
    float* fv   = ts + 11*R64;

    const int MB = NROWS / 64;  // 304

    {
        GemmP A = { emb, {wq, wk, wv}, {bq, bk, bv}, nullptr, {q, k, v}, 64, 64, 0 };
        gemm_kernel<<<dim3(MB, 1, 3), dim3(256), 0, stream>>>(A);
    }
    mha_core_kernel<<<dim3(BBATCH, NHEAD), dim3(256), 0, stream>>>(q, k, v, ctx);
    {
        GemmP A = { ctx, {wo, nullptr, nullptr}, {bo, nullptr, nullptr}, emb,
                    {ctx2, nullptr, nullptr}, 64, 64, 0 };
        gemm_kernel<<<dim3(MB, 1, 1), dim3(256), 0, stream>>>(A);
    }
    {
        GemmP A = { ctx2, {w1, nullptr, nullptr}, {b1, nullptr, nullptr}, nullptr,
                    {hid, nullptr, nullptr}, 64, 256, 1 };
        gemm_kernel<<<dim3(MB, 4, 1), dim3(256), 0, stream>>>(A);
    }
    {
        GemmP A = { hid, {w2, nullptr, nullptr}, {b2, nullptr, nullptr}, ctx2,
                    {ctx3, nullptr, nullptr}, 256, 64, 0 };
        gemm_kernel<<<dim3(MB, 1, 1), dim3(256), 0, stream>>>(A);
    }
    {
        GemmP A = { ctx3, {fak, fav, nullptr}, {fabk, fabv, nullptr}, nullptr,
                    {fk, fv, nullptr}, 64, 64, 0 };
        gemm_kernel<<<dim3(MB, 1, 2), dim3(256), 0, stream>>>(A);
    }
    final_kernel<<<dim3(BBATCH), dim3(128), 0, stream>>>(
        ctx3, fk, fv, faq, fabq, o0w, o0b, o1w, o1b, out);
}

// Round 6
// 601.751 us; speedup vs baseline: 2.2713x; 1.1482x over previous
//
#include <hip/hip_runtime.h>
#include <hip/hip_bf16.h>
#include <cstdint>
#include <cstddef>

#define TT 128
#define BBATCH 256
#define FFEAT 76
#define HDIM 64
#define NHEAD 4
#define DKH 16
#define DFF1 256
#define AH1 8
#define NROWS (BBATCH * FFEAT)   // 19456

#define LOG2E 1.4426950408889634f

typedef __attribute__((ext_vector_type(8))) short bf16x8;
typedef __attribute__((ext_vector_type(4))) float f32x4;

__device__ __forceinline__ float fast_sigmoid(float v) {
    float p = __builtin_amdgcn_exp2f(-v * LOG2E);
    return __builtin_amdgcn_rcpf(1.0f + p);
}
__device__ __forceinline__ float fast_tanh(float v) {
    float p = __builtin_amdgcn_exp2f(v * (2.0f * LOG2E));
    return 1.0f - 2.0f * __builtin_amdgcn_rcpf(1.0f + p);
}
__device__ __forceinline__ short f2bf(float x) {
    __hip_bfloat16 h = __float2bfloat16(x);
    return *reinterpret_cast<short*>(&h);
}
__device__ __forceinline__ float bf2f(unsigned short s) {
    return __uint_as_float(((unsigned)s) << 16);
}
__device__ __forceinline__ unsigned pack_bf16(float a, float b) {
    unsigned ua = (unsigned)(unsigned short)f2bf(a);
    unsigned ub = (unsigned)(unsigned short)f2bf(b);
    return ua | (ub << 16);
}

// ---------------------------------------------------------------------------
// Kernel 1: barrier-free GRU scan. Block = 256 thr = 4 independent waves;
// wave owns 16 batches x all 64 units. Unit permutation u = 4c+sub (tile nt:
// Whh row = gate*64 + 4c + (nt&3)) makes each lane's outputs 4 consecutive
// units per batch -> packed ds_write_b64 h-exchange (4 writes vs 16).
// __launch_bounds__(256,1): full VGPR budget so the 16 gate chains get ILP.
// ---------------------------------------------------------------------------
__global__ __launch_bounds__(256, 1) void gru_scan_kernel(
    const float* __restrict__ x, const float* __restrict__ w_ih,
    const float* __restrict__ w_hh, const float* __restrict__ b_ih,
    const float* __restrict__ b_hh, const float* __restrict__ Wt,
    const float* __restrict__ Wx, int f_base,
    __hip_bfloat16* __restrict__ hs, float* __restrict__ wtil)
{
    const int f_loc = blockIdx.y;
    const int f     = f_base + f_loc;
    const int bblk  = blockIdx.x * 64;
    const int tid   = threadIdx.x;
    const int wave  = tid >> 6;
    const int lane  = tid & 63;
    const int c     = lane & 15;
    const int q     = lane >> 4;
    const int b0    = bblk + wave * 16;

    __shared__ float x_lds[TT][64];
    __shared__ float wt_s[64][8];
    __shared__ float wx_s[64][8];
    __shared__ short hx[4][16][72];     // [wave][local b][unit], pad 72
    __shared__ float q_s[4][16][8];

    for (int i = tid; i < TT * 64; i += 256) {
        int t = i >> 6, b = i & 63;
        x_lds[t][b] = x[((size_t)t * BBATCH + bblk + b) * FFEAT + f];
    }
    for (int i = tid; i < 512; i += 256) {
        ((float*)wt_s)[i] = Wt[(size_t)f * 512 + i];
        ((float*)wx_s)[i] = Wx[(size_t)f * 512 + i];
    }
    for (int i = lane; i < 16 * 72; i += 64) ((short*)hx[wave])[i] = 0;
    __syncthreads();   // the ONLY block barrier

    // B-fragments, permuted: tile nt covers units u = 4c + (nt&3) of gate nt>>2
    bf16x8 bfr[12][2];
    {
        const float* whh_f = w_hh + (size_t)f * 192 * 64;
        #pragma unroll
        for (int nt = 0; nt < 12; ++nt) {
            int gate = nt >> 2, sub = nt & 3;
            const float* row = whh_f + (size_t)(gate * 64 + 4 * c + sub) * 64;
            #pragma unroll
            for (int kq = 0; kq < 2; ++kq) {
                bf16x8 fr;
                #pragma unroll
                for (int j = 0; j < 8; ++j) fr[j] = f2bf(row[kq * 32 + q * 8 + j]);
                bfr[nt][kq] = fr;
            }
        }
    }
    // per-lane gate constants: unit u = 4c + g
    float wihr[4], wihz[4], wihn[4], bR[4], bZ[4], bNX[4], bNH[4];
    #pragma unroll
    for (int g = 0; g < 4; ++g) {
        int u = 4 * c + g;
        wihr[g] = w_ih[f*192 + u];
        wihz[g] = w_ih[f*192 + 64 + u];
        wihn[g] = w_ih[f*192 + 128 + u];
        bR[g]  = b_ih[f*192 + u]      + b_hh[f*192 + u];
        bZ[g]  = b_ih[f*192 + 64 + u] + b_hh[f*192 + 64 + u];
        bNX[g] = b_ih[f*192 + 128 + u];
        bNH[g] = b_hh[f*192 + 128 + u];
    }

    float hprev[4][4];
    #pragma unroll
    for (int g = 0; g < 4; ++g)
        #pragma unroll
        for (int r = 0; r < 4; ++r) hprev[g][r] = 0.f;

    short* hs_s = (short*)hs + (size_t)f_loc * TT * BBATCH * HDIM;

    for (int t = 0; t < TT; ++t) {
        // A-frags: h_{t-1}[b=c][k=q*8+jj], canonical unit order
        bf16x8 a0 = *(const bf16x8*)&hx[wave][c][q * 8];
        bf16x8 a1 = *(const bf16x8*)&hx[wave][c][32 + q * 8];
        if (t > 0) {
            short* dst = hs_s + ((size_t)(t - 1) * BBATCH + b0 + c) * HDIM + q * 8;
            *(bf16x8*)dst = a0;
            *(bf16x8*)(dst + 32) = a1;
        }

        f32x4 acc[12];
        #pragma unroll
        for (int g = 0; g < 4; ++g) {
            acc[g]     = f32x4{bR[g],  bR[g],  bR[g],  bR[g]};
            acc[g + 4] = f32x4{bZ[g],  bZ[g],  bZ[g],  bZ[g]};
            acc[g + 8] = f32x4{bNH[g], bNH[g], bNH[g], bNH[g]};
        }
        #pragma unroll
        for (int nt = 0; nt < 12; ++nt) {
            acc[nt] = __builtin_amdgcn_mfma_f32_16x16x32_bf16(a0, bfr[nt][0], acc[nt], 0, 0, 0);
            acc[nt] = __builtin_amdgcn_mfma_f32_16x16x32_bf16(a1, bfr[nt][1], acc[nt], 0, 0, 0);
        }

        float4 xv = *(const float4*)&x_lds[t][wave * 16 + q * 4];
        float hn4[4][4];
        #pragma unroll
        for (int g = 0; g < 4; ++g) {
            #pragma unroll
            for (int r = 0; r < 4; ++r) {
                float xb = (&xv.x)[r];
                float R  = fmaf(xb, wihr[g], acc[g][r]);
                float Z  = fmaf(xb, wihz[g], acc[g + 4][r]);
                float NX = fmaf(xb, wihn[g], bNX[g]);
                float rg = fast_sigmoid(R);
                float zg = fast_sigmoid(Z);
                float ng = fast_tanh(fmaf(rg, acc[g + 8][r], NX));
                float hn = fmaf(zg, hprev[g][r] - ng, ng);
                hprev[g][r] = hn;
                hn4[g][r] = hn;
            }
        }
        // packed h-exchange: per batch r, units 4c..4c+3 -> one b64 write
        #pragma unroll
        for (int r = 0; r < 4; ++r) {
            uint2 w;
            w.x = pack_bf16(hn4[0][r], hn4[1][r]);
            w.y = pack_bf16(hn4[2][r], hn4[3][r]);
            *(uint2*)&hx[wave][q * 4 + r][4 * c] = w;
        }
        // no barrier: same-wave LDS ordering via lgkmcnt
    }
    // store h_{T-1}
    {
        bf16x8 a0 = *(const bf16x8*)&hx[wave][c][q * 8];
        bf16x8 a1 = *(const bf16x8*)&hx[wave][c][32 + q * 8];
        short* dst = hs_s + ((size_t)(TT - 1) * BBATCH + b0 + c) * HDIM + q * 8;
        *(bf16x8*)dst = a0;
        *(bf16x8*)(dst + 32) = a1;
    }

    // q[b][a] = Wt^T h_127
    #pragma unroll
    for (int rr = 0; rr < 2; ++rr) {
        int role = rr * 64 + lane;
        int b = role >> 3, a = role & 7;
        float s = 0.f;
        #pragma unroll 8
        for (int j = 0; j < 64; ++j)
            s = fmaf(bf2f((unsigned short)hx[wave][b][j]), wt_s[j][a], s);
        q_s[wave][b][a] = s;
    }
    // wtilde[b][j] = sum_a Wx[j][a] * q[b][a]
    {
        int b = lane >> 2, jb = (lane & 3) * 16;
        float qreg[8];
        #pragma unroll
        for (int a = 0; a < 8; ++a) qreg[a] = q_s[wave][b][a];
        float* wt_out = wtil + ((size_t)(b0 + b) * FFEAT + f) * HDIM + jb;
        #pragma unroll
        for (int j4 = 0; j4 < 4; ++j4) {
            float4 v;
            #pragma unroll
            for (int jj = 0; jj < 4; ++jj) {
                int j = jb + j4 * 4 + jj;
                float s = 0.f;
                #pragma unroll
                for (int a = 0; a < 8; ++a) s = fmaf(wx_s[j][a], qreg[a], s);
                (&v.x)[jj] = s;
            }
            *(float4*)&wt_out[j4 * 4] = v;
        }
    }
}

// ---------------------------------------------------------------------------
// Kernel 2: time attention, single HBM read of hs. One wave per (b, f):
// pass 1 reads rows (t=lane, lane+64), computes dp, stages rows in LDS;
// softmax; pass 2 weighted-sums from LDS. No barrier (single wave).
// ---------------------------------------------------------------------------
__global__ __launch_bounds__(64) void attn2_kernel(
    const __hip_bfloat16* __restrict__ hs, const float* __restrict__ wtil,
    const float* __restrict__ rate, int f_base, float* __restrict__ emb)
{
    const int b     = blockIdx.x;
    const int f_loc = blockIdx.y;
    const int f     = f_base + f_loc;
    const int lane  = threadIdx.x;

    __shared__ short h_s[TT][72];   // 18 KB, rows 144 B (16B-aligned)
    __shared__ float a_s[TT];

    float wreg[64];
    {
        const float4* src = (const float4*)(wtil + ((size_t)b * FFEAT + f) * HDIM);
        #pragma unroll
        for (int i = 0; i < 16; ++i) {
            float4 v = src[i];
            wreg[4*i+0] = v.x; wreg[4*i+1] = v.y; wreg[4*i+2] = v.z; wreg[4*i+3] = v.w;
        }
    }
    const float rs = fast_sigmoid(rate[f]);
    const short* hsp = (const short*)hs + (size_t)f_loc * TT * BBATCH * HDIM;

    float e[2];
    #pragma unroll
    for (int half = 0; half < 2; ++half) {
        int t = half * 64 + lane;
        const uint4* row = (const uint4*)(hsp + ((size_t)t * BBATCH + b) * HDIM);
        float dp = 0.f;
        #pragma unroll
        for (int c4 = 0; c4 < 8; ++c4) {
            uint4 u = row[c4];
            *(uint4*)&h_s[t][c4 * 8] = u;      // stage for pass 2
            unsigned vals[4] = {u.x, u.y, u.z, u.w};
            #pragma unroll
            for (int p = 0; p < 4; ++p) {
                dp = fmaf(__uint_as_float(vals[p] << 16),         wreg[c4*8 + 2*p],     dp);
                dp = fmaf(__uint_as_float(vals[p] & 0xffff0000u), wreg[c4*8 + 2*p + 1], dp);
            }
        }
        float sig = fast_sigmoid(dp);
        float den = rs * (__logf(2.72f + (1.0f - sig)) * (float)(TT - t));
        e[half] = fmaxf(sig / den, 0.0f);
    }
    float m = fmaxf(e[0], e[1]);
    #pragma unroll
    for (int off = 32; off > 0; off >>= 1) m = fmaxf(m, __shfl_xor(m, off, 64));
    float p0 = __builtin_amdgcn_exp2f((e[0] - m) * LOG2E);
    float p1 = __builtin_amdgcn_exp2f((e[1] - m) * LOG2E);
    float s = p0 + p1;
    #pragma unroll
    for (int off = 32; off > 0; off >>= 1) s += __shfl_xor(s, off, 64);
    float inv = __builtin_amdgcn_rcpf(s);
    a_s[lane]      = p0 * inv;
    a_s[lane + 64] = p1 * inv;

    // pass 2 from LDS: lane = unit j
    const int j = lane;
    float acc = 0.f;
    #pragma unroll 8
    for (int t = 0; t < TT; ++t)
        acc = fmaf(a_s[t], bf2f((unsigned short)h_s[t][j]), acc);
    emb[((size_t)b * FFEAT + f) * HDIM + j] = acc;
}

// ---------------------------------------------------------------------------
// Tail: tiled GEMM + MHA core + final head (unchanged).
// ---------------------------------------------------------------------------
struct GemmP {
    const float* X;
    const float* W[3];
    const float* B[3];
    const float* R;
    float* Y[3];
    int K;
    int Nfull;
    int act;
};

__global__ __launch_bounds__(256) void gemm_kernel(GemmP A)
{
    __shared__ float xs[64][65];
    __shared__ float ws[64][68];

    const int tid = threadIdx.x;
    const int tx  = tid & 15;
    const int ty  = tid >> 4;
    const int m0  = blockIdx.x * 64;
    const int n0  = blockIdx.y * 64;
    const int z   = blockIdx.z;

    const float* W = A.W[z];
    const float* Bv = A.B[z];
    float* Y = A.Y[z];
    const int K = A.K, Nfull = A.Nfull;

    float acc[4][4];
    #pragma unroll
    for (int i = 0; i < 4; ++i)
        #pragma unroll
        for (int j = 0; j < 4; ++j) acc[i][j] = 0.f;

    for (int kc = 0; kc < K; kc += 64) {
        for (int s = tid; s < 1024; s += 256) {
            int row = s >> 4, c4 = s & 15;
            float4 xv = *(const float4*)&A.X[(size_t)(m0 + row) * K + kc + 4*c4];
            xs[row][4*c4+0] = xv.x; xs[row][4*c4+1] = xv.y;
            xs[row][4*c4+2] = xv.z; xs[row][4*c4+3] = xv.w;
            float4 wv = *(const float4*)&W[(size_t)(kc + row) * Nfull + n0 + 4*c4];
            *(float4*)&ws[row][4*c4] = wv;
        }
        __syncthreads();
        #pragma unroll 16
        for (int k = 0; k < 64; ++k) {
            float a0 = xs[4*ty+0][k], a1 = xs[4*ty+1][k];
            float a2 = xs[4*ty+2][k], a3 = xs[4*ty+3][k];
            float4 wv = *(const float4*)&ws[k][4*tx];
            #pragma unroll
            for (int j = 0; j < 4; ++j) {
                float wj = (&wv.x)[j];
                acc[0][j] = fmaf(a0, wj, acc[0][j]);
                acc[1][j] = fmaf(a1, wj, acc[1][j]);
                acc[2][j] = fmaf(a2, wj, acc[2][j]);
                acc[3][j] = fmaf(a3, wj, acc[3][j]);
            }
        }
        __syncthreads();
    }

    float4 bias = *(const float4*)&Bv[n0 + 4*tx];
    #pragma unroll
    for (int i = 0; i < 4; ++i) {
        int row = m0 + 4*ty + i;
        float4 v;
        v.x = acc[i][0] + bias.x; v.y = acc[i][1] + bias.y;
        v.z = acc[i][2] + bias.z; v.w = acc[i][3] + bias.w;
        if (A.act) {
            v.x = fmaxf(v.x, 0.f); v.y = fmaxf(v.y, 0.f);
            v.z = fmaxf(v.z, 0.f); v.w = fmaxf(v.w, 0.f);
        }
        if (A.R) {
            float4 r4 = *(const float4*)&A.R[(size_t)row * Nfull + n0 + 4*tx];
            v.x += r4.x; v.y += r4.y; v.z += r4.z; v.w += r4.w;
        }
        *(float4*)&Y[(size_t)row * Nfull + n0 + 4*tx] = v;
    }
}

__global__ __launch_bounds__(256) void mha_core_kernel(
    const float* __restrict__ q, const float* __restrict__ k,
    const float* __restrict__ v, float* __restrict__ ctx)
{
    const int b  = blockIdx.x;
    const int hh = blockIdx.y;
    const int tid = threadIdx.x;

    __shared__ float qs[FFEAT][17];
    __shared__ float ks[FFEAT][17];
    __shared__ float vs[FFEAT][17];
    __shared__ float ps[FFEAT][77];

    for (int idx = tid; idx < FFEAT * DKH; idx += 256) {
        int i = idx >> 4, c = idx & 15;
        size_t g = ((size_t)b * FFEAT + i) * HDIM + hh * DKH + c;
        qs[i][c] = q[g]; ks[i][c] = k[g]; vs[i][c] = v[g];
    }
    __syncthreads();

    for (int idx = tid; idx < FFEAT * FFEAT; idx += 256) {
        int i = idx / FFEAT, j = idx % FFEAT;
        float acc = 0.f;
        #pragma unroll
        for (int c = 0; c < DKH; ++c) acc = fmaf(qs[i][c], ks[j][c], acc);
        ps[i][j] = acc * 0.25f;
    }
    __syncthreads();

    if (tid < FFEAT) {
        float mm = ps[tid][0];
        #pragma unroll 4
        for (int j = 1; j < FFEAT; ++j) mm = fmaxf(mm, ps[tid][j]);
        float ss = 0.f;
        #pragma unroll 4
        for (int j = 0; j < FFEAT; ++j) {
            float pv = __builtin_amdgcn_exp2f((ps[tid][j] - mm) * LOG2E);
            ps[tid][j] = pv; ss += pv;
        }
        float inv = 1.0f / ss;
        #pragma unroll 4
        for (int j = 0; j < FFEAT; ++j) ps[tid][j] *= inv;
    }
    __syncthreads();

    for (int idx = tid; idx < FFEAT * DKH; idx += 256) {
        int i = idx >> 4, c = idx & 15;
        float acc = 0.f;
        #pragma unroll 4
        for (int j = 0; j < FFEAT; ++j) acc = fmaf(ps[i][j], vs[j][c], acc);
        ctx[((size_t)b * FFEAT + i) * HDIM + hh * DKH + c] = acc;
    }
}

__global__ __launch_bounds__(128) void final_kernel(
    const float* __restrict__ ctx3, const float* __restrict__ fk,
    const float* __restrict__ fv,
    const float* __restrict__ faq, const float* __restrict__ fabq,
    const float* __restrict__ o0w, const float* __restrict__ o0b,
    const float* __restrict__ o1w, const float* __restrict__ o1b,
    float* __restrict__ out)
{
    const int b = blockIdx.x;
    const int tid = threadIdx.x;

    __shared__ float last[HDIM];
    __shared__ float fqs[HDIM];
    __shared__ float sm[FFEAT];
    __shared__ float vv[HDIM];
    __shared__ float hh[HDIM];
    __shared__ float redm[2], redp[2];

    if (tid < HDIM) last[tid] = ctx3[((size_t)b * FFEAT + FFEAT - 1) * HDIM + tid];
    __syncthreads();
    if (tid < HDIM) {
        float acc = fabq[tid];
        #pragma unroll 8
        for (int j = 0; j < HDIM; ++j) acc = fmaf(last[j], faq[j * HDIM + tid], acc);
        fqs[tid] = acc;
    }
    __syncthreads();

    float e = -3.0e38f;
    if (tid < FFEAT) {
        const float4* kr = (const float4*)&fk[((size_t)b * FFEAT + tid) * HDIM];
        float acc = 0.f;
        #pragma unroll
        for (int c4 = 0; c4 < 16; ++c4) {
            float4 kv = kr[c4];
            acc = fmaf(kv.x, fqs[4*c4+0], acc);
            acc = fmaf(kv.y, fqs[4*c4+1], acc);
            acc = fmaf(kv.z, fqs[4*c4+2], acc);
            acc = fmaf(kv.w, fqs[4*c4+3], acc);
        }
        e = acc;
    }
    float m = e;
    #pragma unroll
    for (int off = 32; off > 0; off >>= 1) m = fmaxf(m, __shfl_xor(m, off, 64));
    if ((tid & 63) == 0) redm[tid >> 6] = m;
    __syncthreads();
    m = fmaxf(redm[0], redm[1]);
    float p = (tid < FFEAT) ? __builtin_amdgcn_exp2f((e - m) * LOG2E) : 0.f;
    float s = p;
    #pragma unroll
    for (int off = 32; off > 0; off >>= 1) s += __shfl_xor(s, off, 64);
    if ((tid & 63) == 0) redp[tid >> 6] = s;
    __syncthreads();
    s = redp[0] + redp[1];
    if (tid < FFEAT) sm[tid] = p / s;
    __syncthreads();

    if (tid < HDIM) {
        float acc = 0.f;
        for (int ff = 0; ff < FFEAT; ++ff)
            acc = fmaf(sm[ff], fv[((size_t)b * FFEAT + ff) * HDIM + tid], acc);
        vv[tid] = acc;
    }
    __syncthreads();
    if (tid < HDIM) {
        float acc = o0b[tid];
        #pragma unroll 8
        for (int j = 0; j < HDIM; ++j) acc = fmaf(vv[j], o0w[j * HDIM + tid], acc);
        hh[tid] = fmaxf(acc, 0.f);
    }
    __syncthreads();
    if (tid < 64) {
        float t = hh[tid] * o1w[tid];
        #pragma unroll
        for (int off = 32; off > 0; off >>= 1) t += __shfl_xor(t, off, 64);
        if (tid == 0) out[b] = fast_sigmoid(t + o1b[0]);
    }
}

__global__ void ws_report_kernel(float* out, int n, float ws_mib) {
    int i = blockIdx.x * blockDim.x + threadIdx.x;
    if (i < n) out[i] = ws_mib;
}

extern "C" void kernel_launch(void* const* d_in, const int* in_sizes, int n_in,
                              void* d_out, int out_size, void* d_ws, size_t ws_size,
                              hipStream_t stream)
{
    const float* x     = (const float*)d_in[0];
    const float* w_ih  = (const float*)d_in[1];
    const float* w_hh  = (const float*)d_in[2];
    const float* b_ih  = (const float*)d_in[3];
    const float* b_hh  = (const float*)d_in[4];
    const float* attWt = (const float*)d_in[5];
    const float* attWx = (const float*)d_in[6];
    const float* attRt = (const float*)d_in[7];
    const float* wq    = (const float*)d_in[8];
    const float* bq    = (const float*)d_in[9];
    const float* wk    = (const float*)d_in[10];
    const float* bk    = (const float*)d_in[11];
    const float* wv    = (const float*)d_in[12];
    const float* bv    = (const float*)d_in[13];
    const float* wo    = (const float*)d_in[14];
    const float* bo    = (const float*)d_in[15];
    const float* w1    = (const float*)d_in[16];
    const float* b1    = (const float*)d_in[17];
    const float* w2    = (const float*)d_in[18];
    const float* b2    = (const float*)d_in[19];
    const float* faq   = (const float*)d_in[20];
    const float* fabq  = (const float*)d_in[21];
    const float* fak   = (const float*)d_in[22];
    const float* fabk  = (const float*)d_in[23];
    const float* fav   = (const float*)d_in[24];
    const float* fabv  = (const float*)d_in[25];
    const float* o0w   = (const float*)d_in[26];
    const float* o0b   = (const float*)d_in[27];
    const float* o1w   = (const float*)d_in[28];
    const float* o1b   = (const float*)d_in[29];
    float* out = (float*)d_out;

    const size_t emb_bytes  = (size_t)NROWS * HDIM * 4;
    const size_t wtil_bytes = (size_t)NROWS * HDIM * 4;
    const size_t R64        = (size_t)NROWS * HDIM;
    const size_t tail_bytes = 12 * R64 * 4;

    const int chunk_opts[6] = {76, 38, 19, 4, 2, 1};
    int FC = 0;
    for (int i = 0; i < 6; ++i) {
        size_t hs_b = (size_t)chunk_opts[i] * BBATCH * TT * HDIM * 2;
        size_t scratch = hs_b > tail_bytes ? hs_b : tail_bytes;
        if (emb_bytes + wtil_bytes + scratch <= ws_size) { FC = chunk_opts[i]; break; }
    }
    if (FC == 0) {
        ws_report_kernel<<<dim3((out_size + 255) / 256), dim3(256), 0, stream>>>(
            out, out_size, (float)((double)ws_size / (1024.0 * 1024.0)));
        return;
    }

    float* emb  = (float*)d_ws;
    float* wtil = (float*)((char*)d_ws + emb_bytes);
    char*  scratch = (char*)d_ws + emb_bytes + wtil_bytes;
    __hip_bfloat16* hs = (__hip_bfloat16*)scratch;

    for (int f0 = 0; f0 < FFEAT; f0 += FC) {
        int fc = (FFEAT - f0 < FC) ? (FFEAT - f0) : FC;
        gru_scan_kernel<<<dim3(4, fc), dim3(256), 0, stream>>>(
            x, w_ih, w_hh, b_ih, b_hh, attWt, attWx, f0, hs, wtil);
        attn2_kernel<<<dim3(BBATCH, fc), dim3(64), 0, stream>>>(
            hs, wtil, attRt, f0, emb);
    }

    float* ts   = (float*)scratch;
    float* q    = ts;
    float* k    = ts + 1*R64;
    float* v    = ts + 2*R64;
    float* ctx  = ts + 3*R64;
    float* ctx2 = ts + 4*R64;
    float* hid  = ts + 5*R64;
    float* ctx3 = ts + 9*R64;
    float* fk   = ts + 10*R64;
    float* fv   = ts + 11*R64;

    const int MB = NROWS / 64;

    {
        GemmP A = { emb, {wq, wk, wv}, {bq, bk, bv}, nullptr, {q, k, v}, 64, 64, 0 };
        gemm_kernel<<<dim3(MB, 1, 3), dim3(256), 0, stream>>>(A);
    }
    mha_core_kernel<<<dim3(BBATCH, NHEAD), dim3(256), 0, stream>>>(q, k, v, ctx);
    {
        GemmP A = { ctx, {wo, nullptr, nullptr}, {bo, nullptr, nullptr}, emb,
                    {ctx2, nullptr, nullptr}, 64, 64, 0 };
        gemm_kernel<<<dim3(MB, 1, 1), dim3(256), 0, stream>>>(A);
    }
    {
        GemmP A = { ctx2, {w1, nullptr, nullptr}, {b1, nullptr, nullptr}, nullptr,
                    {hid, nullptr, nullptr}, 64, 256, 1 };
        gemm_kernel<<<dim3(MB, 4, 1), dim3(256), 0, stream>>>(A);
    }
    {
        GemmP A = { hid, {w2, nullptr, nullptr}, {b2, nullptr, nullptr}, ctx2,
                    {ctx3, nullptr, nullptr}, 256, 64, 0 };
        gemm_kernel<<<dim3(MB, 1, 1), dim3(256), 0, stream>>>(A);
    }
    {
        GemmP A = { ctx3, {fak, fav, nullptr}, {fabk, fabv, nullptr}, nullptr,
                    {fk, fv, nullptr}, 64, 64, 0 };
        gemm_kernel<<<dim3(MB, 1, 2), dim3(256), 0, stream>>>(A);
    }
    final_kernel<<<dim3(BBATCH), dim3(128), 0, stream>>>(
        ctx3, fk, fv, faq, fabq, o0w, o0b, o1w, o1b, out);
}

// Round 7
// 583.701 us; speedup vs baseline: 2.3415x; 1.0309x over previous
//
#include <hip/hip_runtime.h>
#include <hip/hip_bf16.h>
#include <cstdint>
#include <cstddef>

#define TT 128
#define BBATCH 256
#define FFEAT 76
#define HDIM 64
#define NHEAD 4
#define DKH 16
#define DFF1 256
#define AH1 8
#define NROWS (BBATCH * FFEAT)   // 19456

#define LOG2E 1.4426950408889634f

typedef __attribute__((ext_vector_type(8))) short bf16x8;
typedef __attribute__((ext_vector_type(4))) float f32x4;

__device__ __forceinline__ float fast_sigmoid(float v) {
    float p = __builtin_amdgcn_exp2f(-v * LOG2E);
    return __builtin_amdgcn_rcpf(1.0f + p);
}
__device__ __forceinline__ float fast_tanh(float v) {
    float p = __builtin_amdgcn_exp2f(v * (2.0f * LOG2E));
    return 1.0f - 2.0f * __builtin_amdgcn_rcpf(1.0f + p);
}
__device__ __forceinline__ short f2bf(float x) {
    __hip_bfloat16 h = __float2bfloat16(x);
    return *reinterpret_cast<short*>(&h);
}
__device__ __forceinline__ float bf2f(unsigned short s) {
    return __uint_as_float(((unsigned)s) << 16);
}
__device__ __forceinline__ unsigned pack_bf16(float a, float b) {
    unsigned ua = (unsigned)(unsigned short)f2bf(a);
    unsigned ub = (unsigned)(unsigned short)f2bf(b);
    return ua | (ub << 16);
}

// ---------------------------------------------------------------------------
// Kernel 1: ZERO-EXCHANGE GRU scan. Block = 256 thr = 4 independent waves;
// wave owns 16 batches x all 64 units, feature f. Transposed GEMM
// G^T = Whh_perm . h^T : A = static Whh frags (M=192 gate-slots), B = h frags.
// Whh row permutation: tile nt = gate*4+tt, output (quad q, reg r) -> unit
// u = q*8 + (tt&1)*4 + r + (tt>>1)*32. Lane (c=lane&15, q=lane>>4) computes
// gates for batch c, units {q*8..q*8+7, 32+q*8..+7} == exactly its next-step
// B-fragments -> h stays in registers, NO LDS in the scan loop (except x read).
// hs layout [f][b][t][u] so attn2 reads are contiguous per (f,b).
// ---------------------------------------------------------------------------
__global__ __launch_bounds__(256, 1) void gru_scan_kernel(
    const float* __restrict__ x, const float* __restrict__ w_ih,
    const float* __restrict__ w_hh, const float* __restrict__ b_ih,
    const float* __restrict__ b_hh, const float* __restrict__ Wt,
    const float* __restrict__ Wx, int f_base,
    __hip_bfloat16* __restrict__ hs, float* __restrict__ wtil)
{
    const int f_loc = blockIdx.y;
    const int f     = f_base + f_loc;
    const int bblk  = blockIdx.x * 64;
    const int tid   = threadIdx.x;
    const int wave  = tid >> 6;
    const int lane  = tid & 63;
    const int c     = lane & 15;
    const int q     = lane >> 4;
    const int b0    = bblk + wave * 16;

    __shared__ float x_lds[TT][64];
    __shared__ float wt_s[64][8];
    __shared__ float wx_s[64][8];
    __shared__ short hx[4][16][72];
    __shared__ float q_s[4][16][8];

    for (int i = tid; i < TT * 64; i += 256) {
        int t = i >> 6, b = i & 63;
        x_lds[t][b] = x[((size_t)t * BBATCH + bblk + b) * FFEAT + f];
    }
    for (int i = tid; i < 512; i += 256) {
        ((float*)wt_s)[i] = Wt[(size_t)f * 512 + i];
        ((float*)wx_s)[i] = Wx[(size_t)f * 512 + i];
    }
    __syncthreads();   // the ONLY block barrier

    // A-fragments (static Whh, permuted). Tile nt: gate = nt>>2, tt = nt&3.
    // Lane (c,q): A[m=c][k=q*8+j] = Whh[gate*64 + u(c>>2, tt, c&3)][k].
    bf16x8 afr[12][2];
    {
        const float* whh_f = w_hh + (size_t)f * 192 * 64;
        #pragma unroll
        for (int nt = 0; nt < 12; ++nt) {
            int gate = nt >> 2, tt = nt & 3;
            int urow = (c >> 2) * 8 + (tt & 1) * 4 + (c & 3) + (tt >> 1) * 32;
            const float* row = whh_f + (size_t)(gate * 64 + urow) * 64;
            #pragma unroll
            for (int kq = 0; kq < 2; ++kq) {
                bf16x8 fr;
                #pragma unroll
                for (int j = 0; j < 8; ++j) fr[j] = f2bf(row[kq * 32 + q * 8 + j]);
                afr[nt][kq] = fr;
            }
        }
    }
    // per-output constants: output slot (tt, r) -> unit u(q,tt,r), batch c
    float wr[4][4], wz[4][4], wn[4][4], bnx[4][4];
    f32x4 biasv[12];
    #pragma unroll
    for (int tt = 0; tt < 4; ++tt) {
        #pragma unroll
        for (int r = 0; r < 4; ++r) {
            int u = q * 8 + (tt & 1) * 4 + r + (tt >> 1) * 32;
            wr[tt][r]  = w_ih[f*192 + u];
            wz[tt][r]  = w_ih[f*192 + 64 + u];
            wn[tt][r]  = w_ih[f*192 + 128 + u];
            bnx[tt][r] = b_ih[f*192 + 128 + u];
            biasv[tt][r]     = b_ih[f*192 + u]      + b_hh[f*192 + u];
            biasv[4 + tt][r] = b_ih[f*192 + 64 + u] + b_hh[f*192 + 64 + u];
            biasv[8 + tt][r] = b_hh[f*192 + 128 + u];
        }
    }

    float hprev[4][4];
    #pragma unroll
    for (int tt = 0; tt < 4; ++tt)
        #pragma unroll
        for (int r = 0; r < 4; ++r) hprev[tt][r] = 0.f;

    bf16x8 hb0 = {0,0,0,0,0,0,0,0};   // h units q*8..+7, batch c
    bf16x8 hb1 = {0,0,0,0,0,0,0,0};   // h units 32+q*8..+7

    short* hs_b = (short*)hs + ((size_t)f_loc * BBATCH + b0 + c) * TT * HDIM;

    for (int t = 0; t < TT; ++t) {
        f32x4 acc[12];
        #pragma unroll
        for (int nt = 0; nt < 12; ++nt) {
            f32x4 a = __builtin_amdgcn_mfma_f32_16x16x32_bf16(afr[nt][0], hb0, biasv[nt], 0, 0, 0);
            acc[nt]  = __builtin_amdgcn_mfma_f32_16x16x32_bf16(afr[nt][1], hb1, a, 0, 0, 0);
        }

        float xv = x_lds[t][wave * 16 + c];
        float hn4[4][4];
        #pragma unroll
        for (int tt = 0; tt < 4; ++tt) {
            #pragma unroll
            for (int r = 0; r < 4; ++r) {
                float R  = fmaf(xv, wr[tt][r], acc[tt][r]);
                float Z  = fmaf(xv, wz[tt][r], acc[4 + tt][r]);
                float NX = fmaf(xv, wn[tt][r], bnx[tt][r]);
                float rg = fast_sigmoid(R);
                float zg = fast_sigmoid(Z);
                float ng = fast_tanh(fmaf(rg, acc[8 + tt][r], NX));
                float hn = fmaf(zg, hprev[tt][r] - ng, ng);
                hprev[tt][r] = hn;
                hn4[tt][r] = hn;
            }
        }
        // pack next-step B-frags in registers (no LDS!)
        {
            union { int4 i; bf16x8 v; } u0, u1;
            u0.i.x = pack_bf16(hn4[0][0], hn4[0][1]);
            u0.i.y = pack_bf16(hn4[0][2], hn4[0][3]);
            u0.i.z = pack_bf16(hn4[1][0], hn4[1][1]);
            u0.i.w = pack_bf16(hn4[1][2], hn4[1][3]);
            u1.i.x = pack_bf16(hn4[2][0], hn4[2][1]);
            u1.i.y = pack_bf16(hn4[2][2], hn4[2][3]);
            u1.i.z = pack_bf16(hn4[3][0], hn4[3][1]);
            u1.i.w = pack_bf16(hn4[3][2], hn4[3][3]);
            hb0 = u0.v; hb1 = u1.v;
        }
        // store h_t: [f][b0+c][t][u]; 4 q-lanes x 2 instrs fill each 128-B line
        short* dst = hs_b + (size_t)t * HDIM + q * 8;
        *(bf16x8*)dst = hb0;
        *(bf16x8*)(dst + 32) = hb1;
    }

    // expose h_127 to the wave for q/wtilde (one-time LDS, wave-internal)
    *(bf16x8*)&hx[wave][c][q * 8]      = hb0;
    *(bf16x8*)&hx[wave][c][32 + q * 8] = hb1;

    // q[b][a] = Wt^T h_127
    #pragma unroll
    for (int rr = 0; rr < 2; ++rr) {
        int role = rr * 64 + lane;
        int b = role >> 3, a = role & 7;
        float s = 0.f;
        #pragma unroll 8
        for (int j = 0; j < 64; ++j)
            s = fmaf(bf2f((unsigned short)hx[wave][b][j]), wt_s[j][a], s);
        q_s[wave][b][a] = s;
    }
    // wtilde[b][j] = sum_a Wx[j][a] * q[b][a]
    {
        int b = lane >> 2, jb = (lane & 3) * 16;
        float qreg[8];
        #pragma unroll
        for (int a = 0; a < 8; ++a) qreg[a] = q_s[wave][b][a];
        float* wt_out = wtil + ((size_t)(b0 + b) * FFEAT + f) * HDIM + jb;
        #pragma unroll
        for (int j4 = 0; j4 < 4; ++j4) {
            float4 v;
            #pragma unroll
            for (int jj = 0; jj < 4; ++jj) {
                int j = jb + j4 * 4 + jj;
                float s = 0.f;
                #pragma unroll
                for (int a = 0; a < 8; ++a) s = fmaf(wx_s[j][a], qreg[a], s);
                (&v.x)[jj] = s;
            }
            *(float4*)&wt_out[j4 * 4] = v;
        }
    }
}

// ---------------------------------------------------------------------------
// Kernel 2: time attention. hs layout [f][b][t][u] -> contiguous 16 KB per
// block. One wave per (b,f): pass 1 (lane=t) streams rows, computes dp,
// stages in LDS; softmax; pass 2 (lane=u) from LDS. No barrier.
// ---------------------------------------------------------------------------
__global__ __launch_bounds__(64) void attn2_kernel(
    const __hip_bfloat16* __restrict__ hs, const float* __restrict__ wtil,
    const float* __restrict__ rate, int f_base, float* __restrict__ emb)
{
    const int b     = blockIdx.x;
    const int f_loc = blockIdx.y;
    const int f     = f_base + f_loc;
    const int lane  = threadIdx.x;

    __shared__ short h_s[TT][72];
    __shared__ float a_s[TT];

    float wreg[64];
    {
        const float4* src = (const float4*)(wtil + ((size_t)b * FFEAT + f) * HDIM);
        #pragma unroll
        for (int i = 0; i < 16; ++i) {
            float4 v = src[i];
            wreg[4*i+0] = v.x; wreg[4*i+1] = v.y; wreg[4*i+2] = v.z; wreg[4*i+3] = v.w;
        }
    }
    const float rs = fast_sigmoid(rate[f]);
    const short* base = (const short*)hs + ((size_t)f_loc * BBATCH + b) * TT * HDIM;

    float e[2];
    #pragma unroll
    for (int half = 0; half < 2; ++half) {
        int t = half * 64 + lane;
        const uint4* row = (const uint4*)(base + (size_t)t * HDIM);
        float dp = 0.f;
        #pragma unroll
        for (int c4 = 0; c4 < 8; ++c4) {
            uint4 u = row[c4];
            *(uint4*)&h_s[t][c4 * 8] = u;
            unsigned vals[4] = {u.x, u.y, u.z, u.w};
            #pragma unroll
            for (int p = 0; p < 4; ++p) {
                dp = fmaf(__uint_as_float(vals[p] << 16),         wreg[c4*8 + 2*p],     dp);
                dp = fmaf(__uint_as_float(vals[p] & 0xffff0000u), wreg[c4*8 + 2*p + 1], dp);
            }
        }
        float sig = fast_sigmoid(dp);
        float den = rs * (__logf(2.72f + (1.0f - sig)) * (float)(TT - t));
        e[half] = fmaxf(sig / den, 0.0f);
    }
    float m = fmaxf(e[0], e[1]);
    #pragma unroll
    for (int off = 32; off > 0; off >>= 1) m = fmaxf(m, __shfl_xor(m, off, 64));
    float p0 = __builtin_amdgcn_exp2f((e[0] - m) * LOG2E);
    float p1 = __builtin_amdgcn_exp2f((e[1] - m) * LOG2E);
    float s = p0 + p1;
    #pragma unroll
    for (int off = 32; off > 0; off >>= 1) s += __shfl_xor(s, off, 64);
    float inv = __builtin_amdgcn_rcpf(s);
    a_s[lane]      = p0 * inv;
    a_s[lane + 64] = p1 * inv;

    const int j = lane;
    float acc = 0.f;
    #pragma unroll 8
    for (int t = 0; t < TT; ++t)
        acc = fmaf(a_s[t], bf2f((unsigned short)h_s[t][j]), acc);
    emb[((size_t)b * FFEAT + f) * HDIM + j] = acc;
}

// ---------------------------------------------------------------------------
// Tail: tiled GEMM + MHA core + final head (unchanged).
// ---------------------------------------------------------------------------
struct GemmP {
    const float* X;
    const float* W[3];
    const float* B[3];
    const float* R;
    float* Y[3];
    int K;
    int Nfull;
    int act;
};

__global__ __launch_bounds__(256) void gemm_kernel(GemmP A)
{
    __shared__ float xs[64][65];
    __shared__ float ws[64][68];

    const int tid = threadIdx.x;
    const int tx  = tid & 15;
    const int ty  = tid >> 4;
    const int m0  = blockIdx.x * 64;
    const int n0  = blockIdx.y * 64;
    const int z   = blockIdx.z;

    const float* W = A.W[z];
    const float* Bv = A.B[z];
    float* Y = A.Y[z];
    const int K = A.K, Nfull = A.Nfull;

    float acc[4][4];
    #pragma unroll
    for (int i = 0; i < 4; ++i)
        #pragma unroll
        for (int j = 0; j < 4; ++j) acc[i][j] = 0.f;

    for (int kc = 0; kc < K; kc += 64) {
        for (int s = tid; s < 1024; s += 256) {
            int row = s >> 4, c4 = s & 15;
            float4 xv = *(const float4*)&A.X[(size_t)(m0 + row) * K + kc + 4*c4];
            xs[row][4*c4+0] = xv.x; xs[row][4*c4+1] = xv.y;
            xs[row][4*c4+2] = xv.z; xs[row][4*c4+3] = xv.w;
            float4 wv = *(const float4*)&W[(size_t)(kc + row) * Nfull + n0 + 4*c4];
            *(float4*)&ws[row][4*c4] = wv;
        }
        __syncthreads();
        #pragma unroll 16
        for (int k = 0; k < 64; ++k) {
            float a0 = xs[4*ty+0][k], a1 = xs[4*ty+1][k];
            float a2 = xs[4*ty+2][k], a3 = xs[4*ty+3][k];
            float4 wv = *(const float4*)&ws[k][4*tx];
            #pragma unroll
            for (int j = 0; j < 4; ++j) {
                float wj = (&wv.x)[j];
                acc[0][j] = fmaf(a0, wj, acc[0][j]);
                acc[1][j] = fmaf(a1, wj, acc[1][j]);
                acc[2][j] = fmaf(a2, wj, acc[2][j]);
                acc[3][j] = fmaf(a3, wj, acc[3][j]);
            }
        }
        __syncthreads();
    }

    float4 bias = *(const float4*)&Bv[n0 + 4*tx];
    #pragma unroll
    for (int i = 0; i < 4; ++i) {
        int row = m0 + 4*ty + i;
        float4 v;
        v.x = acc[i][0] + bias.x; v.y = acc[i][1] + bias.y;
        v.z = acc[i][2] + bias.z; v.w = acc[i][3] + bias.w;
        if (A.act) {
            v.x = fmaxf(v.x, 0.f); v.y = fmaxf(v.y, 0.f);
            v.z = fmaxf(v.z, 0.f); v.w = fmaxf(v.w, 0.f);
        }
        if (A.R) {
            float4 r4 = *(const float4*)&A.R[(size_t)row * Nfull + n0 + 4*tx];
            v.x += r4.x; v.y += r4.y; v.z += r4.z; v.w += r4.w;
        }
        *(float4*)&Y[(size_t)row * Nfull + n0 + 4*tx] = v;
    }
}

__global__ __launch_bounds__(256) void mha_core_kernel(
    const float* __restrict__ q, const float* __restrict__ k,
    const float* __restrict__ v, float* __restrict__ ctx)
{
    const int b  = blockIdx.x;
    const int hh = blockIdx.y;
    const int tid = threadIdx.x;

    __shared__ float qs[FFEAT][17];
    __shared__ float ks[FFEAT][17];
    __shared__ float vs[FFEAT][17];
    __shared__ float ps[FFEAT][77];

    for (int idx = tid; idx < FFEAT * DKH; idx += 256) {
        int i = idx >> 4, c = idx & 15;
        size_t g = ((size_t)b * FFEAT + i) * HDIM + hh * DKH + c;
        qs[i][c] = q[g]; ks[i][c] = k[g]; vs[i][c] = v[g];
    }
    __syncthreads();

    for (int idx = tid; idx < FFEAT * FFEAT; idx += 256) {
        int i = idx / FFEAT, j = idx % FFEAT;
        float acc = 0.f;
        #pragma unroll
        for (int c = 0; c < DKH; ++c) acc = fmaf(qs[i][c], ks[j][c], acc);
        ps[i][j] = acc * 0.25f;
    }
    __syncthreads();

    if (tid < FFEAT) {
        float mm = ps[tid][0];
        #pragma unroll 4
        for (int j = 1; j < FFEAT; ++j) mm = fmaxf(mm, ps[tid][j]);
        float ss = 0.f;
        #pragma unroll 4
        for (int j = 0; j < FFEAT; ++j) {
            float pv = __builtin_amdgcn_exp2f((ps[tid][j] - mm) * LOG2E);
            ps[tid][j] = pv; ss += pv;
        }
        float inv = 1.0f / ss;
        #pragma unroll 4
        for (int j = 0; j < FFEAT; ++j) ps[tid][j] *= inv;
    }
    __syncthreads();

    for (int idx = tid; idx < FFEAT * DKH; idx += 256) {
        int i = idx >> 4, c = idx & 15;
        float acc = 0.f;
        #pragma unroll 4
        for (int j = 0; j < FFEAT; ++j) acc = fmaf(ps[i][j], vs[j][c], acc);
        ctx[((size_t)b * FFEAT + i) * HDIM + hh * DKH + c] = acc;
    }
}

__global__ __launch_bounds__(128) void final_kernel(
    const float* __restrict__ ctx3, const float* __restrict__ fk,
    const float* __restrict__ fv,
    const float* __restrict__ faq, const float* __restrict__ fabq,
    const float* __restrict__ o0w, const float* __restrict__ o0b,
    const float* __restrict__ o1w, const float* __restrict__ o1b,
    float* __restrict__ out)
{
    const int b = blockIdx.x;
    const int tid = threadIdx.x;

    __shared__ float last[HDIM];
    __shared__ float fqs[HDIM];
    __shared__ float sm[FFEAT];
    __shared__ float vv[HDIM];
    __shared__ float hh[HDIM];
    __shared__ float redm[2], redp[2];

    if (tid < HDIM) last[tid] = ctx3[((size_t)b * FFEAT + FFEAT - 1) * HDIM + tid];
    __syncthreads();
    if (tid < HDIM) {
        float acc = fabq[tid];
        #pragma unroll 8
        for (int j = 0; j < HDIM; ++j) acc = fmaf(last[j], faq[j * HDIM + tid], acc);
        fqs[tid] = acc;
    }
    __syncthreads();

    float e = -3.0e38f;
    if (tid < FFEAT) {
        const float4* kr = (const float4*)&fk[((size_t)b * FFEAT + tid) * HDIM];
        float acc = 0.f;
        #pragma unroll
        for (int c4 = 0; c4 < 16; ++c4) {
            float4 kv = kr[c4];
            acc = fmaf(kv.x, fqs[4*c4+0], acc);
            acc = fmaf(kv.y, fqs[4*c4+1], acc);
            acc = fmaf(kv.z, fqs[4*c4+2], acc);
            acc = fmaf(kv.w, fqs[4*c4+3], acc);
        }
        e = acc;
    }
    float m = e;
    #pragma unroll
    for (int off = 32; off > 0; off >>= 1) m = fmaxf(m, __shfl_xor(m, off, 64));
    if ((tid & 63) == 0) redm[tid >> 6] = m;
    __syncthreads();
    m = fmaxf(redm[0], redm[1]);
    float p = (tid < FFEAT) ? __builtin_amdgcn_exp2f((e - m) * LOG2E) : 0.f;
    float s = p;
    #pragma unroll
    for (int off = 32; off > 0; off >>= 1) s += __shfl_xor(s, off, 64);
    if ((tid & 63) == 0) redp[tid >> 6] = s;
    __syncthreads();
    s = redp[0] + redp[1];
    if (tid < FFEAT) sm[tid] = p / s;
    __syncthreads();

    if (tid < HDIM) {
        float acc = 0.f;
        for (int ff = 0; ff < FFEAT; ++ff)
            acc = fmaf(sm[ff], fv[((size_t)b * FFEAT + ff) * HDIM + tid], acc);
        vv[tid] = acc;
    }
    __syncthreads();
    if (tid < HDIM) {
        float acc = o0b[tid];
        #pragma unroll 8
        for (int j = 0; j < HDIM; ++j) acc = fmaf(vv[j], o0w[j * HDIM + tid], acc);
        hh[tid] = fmaxf(acc, 0.f);
    }
    __syncthreads();
    if (tid < 64) {
        float t = hh[tid] * o1w[tid];
        #pragma unroll
        for (int off = 32; off > 0; off >>= 1) t += __shfl_xor(t, off, 64);
        if (tid == 0) out[b] = fast_sigmoid(t + o1b[0]);
    }
}

__global__ void ws_report_kernel(float* out, int n, float ws_mib) {
    int i = blockIdx.x * blockDim.x + threadIdx.x;
    if (i < n) out[i] = ws_mib;
}

extern "C" void kernel_launch(void* const* d_in, const int* in_sizes, int n_in,
                              void* d_out, int out_size, void* d_ws, size_t ws_size,
                              hipStream_t stream)
{
    const float* x     = (const float*)d_in[0];
    const float* w_ih  = (const float*)d_in[1];
    const float* w_hh  = (const float*)d_in[2];
    const float* b_ih  = (const float*)d_in[3];
    const float* b_hh  = (const float*)d_in[4];
    const float* attWt = (const float*)d_in[5];
    const float* attWx = (const float*)d_in[6];
    const float* attRt = (const float*)d_in[7];
    const float* wq    = (const float*)d_in[8];
    const float* bq    = (const float*)d_in[9];
    const float* wk    = (const float*)d_in[10];
    const float* bk    = (const float*)d_in[11];
    const float* wv    = (const float*)d_in[12];
    const float* bv    = (const float*)d_in[13];
    const float* wo    = (const float*)d_in[14];
    const float* bo    = (const float*)d_in[15];
    const float* w1    = (const float*)d_in[16];
    const float* b1    = (const float*)d_in[17];
    const float* w2    = (const float*)d_in[18];
    const float* b2    = (const float*)d_in[19];
    const float* faq   = (const float*)d_in[20];
    const float* fabq  = (const float*)d_in[21];
    const float* fak   = (const float*)d_in[22];
    const float* fabk  = (const float*)d_in[23];
    const float* fav   = (const float*)d_in[24];
    const float* fabv  = (const float*)d_in[25];
    const float* o0w   = (const float*)d_in[26];
    const float* o0b   = (const float*)d_in[27];
    const float* o1w   = (const float*)d_in[28];
    const float* o1b   = (const float*)d_in[29];
    float* out = (float*)d_out;

    const size_t emb_bytes  = (size_t)NROWS * HDIM * 4;
    const size_t wtil_bytes = (size_t)NROWS * HDIM * 4;
    const size_t R64        = (size_t)NROWS * HDIM;
    const size_t tail_bytes = 12 * R64 * 4;

    const int chunk_opts[6] = {76, 38, 19, 4, 2, 1};
    int FC = 0;
    for (int i = 0; i < 6; ++i) {
        size_t hs_b = (size_t)chunk_opts[i] * BBATCH * TT * HDIM * 2;
        size_t scratch = hs_b > tail_bytes ? hs_b : tail_bytes;
        if (emb_bytes + wtil_bytes + scratch <= ws_size) { FC = chunk_opts[i]; break; }
    }
    if (FC == 0) {
        ws_report_kernel<<<dim3((out_size + 255) / 256), dim3(256), 0, stream>>>(
            out, out_size, (float)((double)ws_size / (1024.0 * 1024.0)));
        return;
    }

    float* emb  = (float*)d_ws;
    float* wtil = (float*)((char*)d_ws + emb_bytes);
    char*  scratch = (char*)d_ws + emb_bytes + wtil_bytes;
    __hip_bfloat16* hs = (__hip_bfloat16*)scratch;

    for (int f0 = 0; f0 < FFEAT; f0 += FC) {
        int fc = (FFEAT - f0 < FC) ? (FFEAT - f0) : FC;
        gru_scan_kernel<<<dim3(4, fc), dim3(256), 0, stream>>>(
            x, w_ih, w_hh, b_ih, b_hh, attWt, attWx, f0, hs, wtil);
        attn2_kernel<<<dim3(BBATCH, fc), dim3(64), 0, stream>>>(
            hs, wtil, attRt, f0, emb);
    }

    float* ts   = (float*)scratch;
    float* q    = ts;
    float* k    = ts + 1*R64;
    float* v    = ts + 2*R64;
    float* ctx  = ts + 3*R64;
    float* ctx2 = ts + 4*R64;
    float* hid  = ts + 5*R64;
    float* ctx3 = ts + 9*R64;
    float* fk   = ts + 10*R64;
    float* fv   = ts + 11*R64;

    const int MB = NROWS / 64;

    {
        GemmP A = { emb, {wq, wk, wv}, {bq, bk, bv}, nullptr, {q, k, v}, 64, 64, 0 };
        gemm_kernel<<<dim3(MB, 1, 3), dim3(256), 0, stream>>>(A);
    }
    mha_core_kernel<<<dim3(BBATCH, NHEAD), dim3(256), 0, stream>>>(q, k, v, ctx);
    {
        GemmP A = { ctx, {wo, nullptr, nullptr}, {bo, nullptr, nullptr}, emb,
                    {ctx2, nullptr, nullptr}, 64, 64, 0 };
        gemm_kernel<<<dim3(MB, 1, 1), dim3(256), 0, stream>>>(A);
    }
    {
        GemmP A = { ctx2, {w1, nullptr, nullptr}, {b1, nullptr, nullptr}, nullptr,
                    {hid, nullptr, nullptr}, 64, 256, 1 };
        gemm_kernel<<<dim3(MB, 4, 1), dim3(256), 0, stream>>>(A);
    }
    {
        GemmP A = { hid, {w2, nullptr, nullptr}, {b2, nullptr, nullptr}, ctx2,
                    {ctx3, nullptr, nullptr}, 256, 64, 0 };
        gemm_kernel<<<dim3(MB, 1, 1), dim3(256), 0, stream>>>(A);
    }
    {
        GemmP A = { ctx3, {fak, fav, nullptr}, {fabk, fabv, nullptr}, nullptr,
                    {fk, fv, nullptr}, 64, 64, 0 };
        gemm_kernel<<<dim3(MB, 1, 2), dim3(256), 0, stream>>>(A);
    }
    final_kernel<<<dim3(BBATCH), dim3(128), 0, stream>>>(
        ctx3, fk, fv, faq, fabq, o0w, o0b, o1w, o1b, out);
}